// Round 5
// baseline (163.490 us; speedup 1.0000x reference)
//
#include <hip/hip_runtime.h>
#include <math.h>

#define B_   2
#define C_   128
#define S_   64
#define H_   128
#define W_   512
#define M_   (S_ * S_)   // 4096
#define MID_ 32
#define EPS_ 1e-5f
#define CAP_ 192         // bucket capacity; E[n]=8 (Poisson), overflow ~impossible

#define KB3 (B_ * H_ * (W_ / 64))   // 2048 k-blocks (64 w-positions each)
#define QB3 (B_ * (M_ / 64))        // 128 q-blocks  (64 m-positions each)

// ---------------------------------------------------------------------------
// Prep: gw = g@W, bw = b@W + bias for both weight sets (block 0: k, 1: q).
// Coalesced element-parallel: thread t owns elements t+256k -> all same j=t&31.
// Block 0 also zeroes the bucket counters (replaces the memset dispatch).
// prepbuf layout: [gw_k(32) | bw_k(32) | gw_q(32) | bw_q(32)]
// ---------------------------------------------------------------------------
__global__ __launch_bounds__(256) void prep_kernel(
    const float* __restrict__ ln_k_g, const float* __restrict__ ln_k_b,
    const float* __restrict__ wk, const float* __restrict__ bk,
    const float* __restrict__ ln_q_g, const float* __restrict__ ln_q_b,
    const float* __restrict__ wq, const float* __restrict__ bq,
    float* __restrict__ prepbuf,
    int* __restrict__ counts)          // [B*W]
{
    const int tid = threadIdx.x;
    const int blk = blockIdx.x;        // 0: k set, 1: q set
    const float* g    = blk ? ln_q_g : ln_k_g;
    const float* bl   = blk ? ln_q_b : ln_k_b;
    const float* wt   = blk ? wq     : wk;
    const float* bias = blk ? bq     : bk;

    __shared__ float pa[256], pb[256];

    float a = 0.f, c2 = 0.f;
#pragma unroll
    for (int k = 0; k < 16; ++k) {
        const int idx = tid + 256 * k;       // coalesced
        const float wv = wt[idx];
        const int c = idx >> 5;
        a  = fmaf(g[c],  wv, a);
        c2 = fmaf(bl[c], wv, c2);
    }
    pa[tid] = a; pb[tid] = c2;

    if (blk == 0) {                          // zero 1024 counters
        ((int4*)counts)[tid] = make_int4(0, 0, 0, 0);
    }
    __syncthreads();

    if (tid < 32) {
        float s = 0.f, t = 0.f;
#pragma unroll
        for (int r = 0; r < 8; ++r) { s += pa[tid + 32 * r]; t += pb[tid + 32 * r]; }
        prepbuf[blk * 64 + tid]      = s;
        prepbuf[blk * 64 + 32 + tid] = t + bias[tid];
    }
}

// ---------------------------------------------------------------------------
// Projection, split-C over 4 waves. All 32 x-values prefetched upfront
// (one latency exposure), weights via wave-uniform s_load, gw/bw from prep.
// ---------------------------------------------------------------------------
__global__ __launch_bounds__(256) void proj_kernel(
    const float* __restrict__ grd_x,   // [B, C, H, W]
    const float* __restrict__ sat_x,   // [B, C, M]
    const float* __restrict__ ln_k_g, const float* __restrict__ wk,
    const float* __restrict__ ln_q_g, const float* __restrict__ wq,
    const float* __restrict__ prepbuf, // [4][32]
    float* __restrict__ kw,            // [B, W, H, MID]
    float* __restrict__ qv)            // [B, M, MID]
{
    __shared__ float4 accS[4][64][4];       // 16 KB, f4-swizzled half-buffer
    __shared__ float2 sAB[4][64];           // 2 KB  (s1, s2 partials)
    __shared__ float  msS[64], rsS[64];

    const int tid  = threadIdx.x;
    const int lane = tid & 63;
    const int wv   = __builtin_amdgcn_readfirstlane(tid >> 6);  // wave-uniform
    const int blk  = blockIdx.x;
    const bool is_k = (blk < KB3);

    const float* gl = is_k ? ln_k_g : ln_q_g;
    const float* wt = is_k ? wk     : wq;
    const int setoff = is_k ? 0 : 64;

    // geometry
    int b, h = 0, pos0;
    const float* xbase;
    size_t xstr;
    if (is_k) {
        const int wchunk = blk & 7;
        h    = (blk >> 3) & (H_ - 1);
        b    = blk >> 10;
        pos0 = wchunk * 64;
        xbase = grd_x + (size_t)b * C_ * H_ * W_ + (size_t)h * W_ + pos0 + lane;
        xstr  = (size_t)H_ * W_;
    } else {
        const int qblk = blk - KB3;
        b    = qblk >> 6;
        pos0 = (qblk & 63) * 64;
        xbase = sat_x + (size_t)b * C_ * M_ + pos0 + lane;
        xstr  = (size_t)M_;
    }

    const float* xp   = xbase + (size_t)(wv * 32) * xstr;
    const float* wrow = wt + (size_t)(wv * 32) * MID_;    // wave-uniform
    const float* grow = gl + wv * 32;                     // wave-uniform

    // ---- prefetch ALL 32 x (32 outstanding loads, one latency hit) ----
    float xv[32];
#pragma unroll
    for (int c = 0; c < 32; ++c) xv[c] = xp[(size_t)c * xstr];

    float acc[MID_];
#pragma unroll
    for (int j = 0; j < MID_; ++j) acc[j] = 0.f;
    float s1 = 0.f, s2 = 0.f;

#pragma unroll
    for (int c = 0; c < 32; ++c) {
        const float x = xv[c];
        s1 += x;
        s2  = fmaf(x, x, s2);
        const float xg = x * grow[c];        // uniform -> SGPR
        const float* wr = wrow + c * MID_;   // uniform row -> s_load
#pragma unroll
        for (int j = 0; j < MID_; ++j)
            acc[j] = fmaf(xg, wr[j], acc[j]);
    }

    // ---- stage partials: s1/s2 + acc half 0 (j 0..15) ----
    sAB[wv][lane] = make_float2(s1, s2);
#pragma unroll
    for (int j4 = 0; j4 < 4; ++j4)
        accS[wv][lane][(j4 + lane) & 3] =
            make_float4(acc[j4 * 4 + 0], acc[j4 * 4 + 1],
                        acc[j4 * 4 + 2], acc[j4 * 4 + 3]);
    __syncthreads();

    // ---- mean/rstd ----
    if (tid < 64) {
        float a = 0.f, c2 = 0.f;
#pragma unroll
        for (int w2 = 0; w2 < 4; ++w2) { a += sAB[w2][tid].x; c2 += sAB[w2][tid].y; }
        const float mean = a * (1.f / C_);
        const float var  = fmaf(-mean, mean, c2 * (1.f / C_));
        msS[tid] = mean;
        rsS[tid] = rsqrtf(var + EPS_);
    }
    __syncthreads();

    // ---- reduce + LN + store, phase 0 (j 0..15) ----
    const int pos = tid >> 2;
    const int jq  = tid & 3;
    float* orow;
    if (is_k) orow = kw + (((size_t)b * W_ + pos0 + pos) * H_ + h) * MID_;
    else      orow = qv + ((size_t)(b << 12) + pos0 + pos) * MID_;
    const float mean = msS[pos];
    const float rstd = rsS[pos];

    {
        float4 r = accS[0][pos][(jq + pos) & 3];
#pragma unroll
        for (int w2 = 1; w2 < 4; ++w2) {
            const float4 t = accS[w2][pos][(jq + pos) & 3];
            r.x += t.x; r.y += t.y; r.z += t.z; r.w += t.w;
        }
        const int j0 = jq * 4;
        const float4 gw4 = *(const float4*)(prepbuf + setoff + j0);
        const float4 bw4 = *(const float4*)(prepbuf + setoff + 32 + j0);
        float4 o;
        o.x = fmaf(rstd, fmaf(-mean, gw4.x, r.x), bw4.x);
        o.y = fmaf(rstd, fmaf(-mean, gw4.y, r.y), bw4.y);
        o.z = fmaf(rstd, fmaf(-mean, gw4.z, r.z), bw4.z);
        o.w = fmaf(rstd, fmaf(-mean, gw4.w, r.w), bw4.w);
        *(float4*)(orow + j0) = o;
    }
    __syncthreads();

    // ---- stage acc half 1 (j 16..31) ----
#pragma unroll
    for (int j4 = 0; j4 < 4; ++j4)
        accS[wv][lane][(j4 + lane) & 3] =
            make_float4(acc[16 + j4 * 4 + 0], acc[16 + j4 * 4 + 1],
                        acc[16 + j4 * 4 + 2], acc[16 + j4 * 4 + 3]);
    __syncthreads();

    {
        float4 r = accS[0][pos][(jq + pos) & 3];
#pragma unroll
        for (int w2 = 1; w2 < 4; ++w2) {
            const float4 t = accS[w2][pos][(jq + pos) & 3];
            r.x += t.x; r.y += t.y; r.z += t.z; r.w += t.w;
        }
        const int j0 = 16 + jq * 4;
        const float4 gw4 = *(const float4*)(prepbuf + setoff + j0);
        const float4 bw4 = *(const float4*)(prepbuf + setoff + 32 + j0);
        float4 o;
        o.x = fmaf(rstd, fmaf(-mean, gw4.x, r.x), bw4.x);
        o.y = fmaf(rstd, fmaf(-mean, gw4.y, r.y), bw4.y);
        o.z = fmaf(rstd, fmaf(-mean, gw4.z, r.z), bw4.z);
        o.w = fmaf(rstd, fmaf(-mean, gw4.w, r.w), bw4.w);
        *(float4*)(orow + j0) = o;
    }
}

// ---------------------------------------------------------------------------
// Bucket build (runs AFTER proj so the overflow fallback is safe).
// ---------------------------------------------------------------------------
__global__ __launch_bounds__(256) void count_kernel(
    const int*   __restrict__ u,       // [B, M]
    const float* __restrict__ qv,      // [B, M, MID]  (fallback only)
    const float* __restrict__ kw,      // [B, W, H, MID] (fallback only)
    const float* __restrict__ gh,      // [B, 1, H, W]   (fallback only)
    int* __restrict__ counts,          // [B*W]
    int* __restrict__ bucket,          // [B*W][CAP_]
    float* __restrict__ out)           // [B, M]
{
    const int bm = blockIdx.x * 256 + threadIdx.x;   // 0..8191
    const int b  = bm >> 12;
    int w = u[bm];
    w = min(max(w, 0), W_ - 1);
    const int bw  = b * W_ + w;
    const int pos = atomicAdd(&counts[bw], 1);
    if (pos < CAP_) {
        bucket[bw * CAP_ + pos] = bm;
    } else {
        // dead in practice — online-softmax scalar fallback
        const float* qr = qv + (size_t)bm * MID_;
        const float* kr = kw + (size_t)bw * H_ * MID_;
        float mx = -1e30f, s = 0.f, sv = 0.f;
        for (int h = 0; h < H_; ++h) {
            float d = 0.f;
            for (int j = 0; j < MID_; ++j) d = fmaf(qr[j], kr[h * MID_ + j], d);
            d *= 0.17677669529663687f;
            const float nm   = fmaxf(mx, d);
            const float corr = __expf(mx - nm);
            const float e    = __expf(d - nm);
            s  = fmaf(s,  corr, e);
            sv = fmaf(sv, corr, e * gh[((size_t)b * H_ + h) * W_ + w]);
            mx = nm;
        }
        out[bm] = sv / s;
    }
}

// ---------------------------------------------------------------------------
// Bucketed attention: block per (b,w); each wave hoists its k fragment and
// v values ONCE, then loops over the bucket's m's (q via s_load + shuffles).
// ---------------------------------------------------------------------------
__global__ __launch_bounds__(256) void battn_kernel(
    const float* __restrict__ qv,      // [B, M, MID]
    const float* __restrict__ kw,      // [B, W, H, MID]
    const float* __restrict__ gh,      // [B, 1, H, W]
    const int*   __restrict__ counts,  // [B*W]
    const int*   __restrict__ bucket,  // [B*W][CAP_]
    float* __restrict__ out)           // [B, M]
{
    const int blk = blockIdx.x;                      // b*W + w
    const int n   = min(counts[blk], CAP_);
    const int tid  = threadIdx.x;
    const int lane = tid & 63;
    const int wv   = __builtin_amdgcn_readfirstlane(tid >> 6);
    if (wv >= n) return;                             // wave-uniform exit

    const int b = blk >> 9;
    const int w = blk & (W_ - 1);

    const float4* k4 = (const float4*)(kw + (size_t)blk * H_ * MID_);
    float4 ka[8], kb[8];
#pragma unroll
    for (int j = 0; j < 8; ++j) ka[j] = k4[lane * 8 + j];
#pragma unroll
    for (int j = 0; j < 8; ++j) kb[j] = k4[(lane + 64) * 8 + j];

    const float v0 = gh[((size_t)b * H_ + lane) * W_ + w];
    const float v1 = gh[((size_t)b * H_ + lane + 64) * W_ + w];

    const int* bkt = bucket + (size_t)blk * CAP_;
    const float sc = 0.17677669529663687f;           // 32^-0.5

    for (int i = wv; i < n; i += 4) {
        const int bm = bkt[i];                       // wave-uniform -> s_load
        const float* qr = qv + (size_t)bm * MID_;    // uniform -> s_load
        float sq[MID_];
#pragma unroll
        for (int j = 0; j < MID_; ++j) sq[j] = qr[j];

        float d0 = 0.f, d1 = 0.f;
#pragma unroll
        for (int j = 0; j < 8; ++j) {
            d0 = fmaf(sq[j * 4 + 0], ka[j].x, d0);
            d0 = fmaf(sq[j * 4 + 1], ka[j].y, d0);
            d0 = fmaf(sq[j * 4 + 2], ka[j].z, d0);
            d0 = fmaf(sq[j * 4 + 3], ka[j].w, d0);
            d1 = fmaf(sq[j * 4 + 0], kb[j].x, d1);
            d1 = fmaf(sq[j * 4 + 1], kb[j].y, d1);
            d1 = fmaf(sq[j * 4 + 2], kb[j].z, d1);
            d1 = fmaf(sq[j * 4 + 3], kb[j].w, d1);
        }
        d0 *= sc; d1 *= sc;

        float mx = fmaxf(d0, d1);
#pragma unroll
        for (int o = 32; o > 0; o >>= 1) mx = fmaxf(mx, __shfl_xor(mx, o, 64));

        const float e0 = __expf(d0 - mx);
        const float e1 = __expf(d1 - mx);
        float s   = e0 + e1;
        float svv = fmaf(e0, v0, e1 * v1);
#pragma unroll
        for (int o = 32; o > 0; o >>= 1) {
            s   += __shfl_xor(s,   o, 64);
            svv += __shfl_xor(svv, o, 64);
        }

        if (lane == 0) out[bm] = svv / s;
    }
}

// ---------------------------------------------------------------------------
extern "C" void kernel_launch(void* const* d_in, const int* in_sizes, int n_in,
                              void* d_out, int out_size, void* d_ws, size_t ws_size,
                              hipStream_t stream) {
    const float* sat_x      = (const float*)d_in[0];
    const float* grd_x      = (const float*)d_in[1];
    const float* grd_height = (const float*)d_in[2];
    const int*   u          = (const int*)d_in[3];
    const float* ln_q_g     = (const float*)d_in[4];
    const float* ln_q_b     = (const float*)d_in[5];
    const float* wq         = (const float*)d_in[6];
    const float* bq         = (const float*)d_in[7];
    const float* ln_k_g     = (const float*)d_in[8];
    const float* ln_k_b     = (const float*)d_in[9];
    const float* wk         = (const float*)d_in[10];
    const float* bk         = (const float*)d_in[11];

    float* out = (float*)d_out;

    // workspace layout
    char* ws = (char*)d_ws;
    float* kw      = (float*)ws;                                  // 16 MB
    float* q       = (float*)(ws + (size_t)16 * 1024 * 1024);     // 1 MB
    int*   counts  = (int*)  (ws + (size_t)17 * 1024 * 1024);     // 4 KB
    int*   bucket  = counts + B_ * W_;                            // 768 KB
    float* prepbuf = (float*)(ws + (size_t)18 * 1024 * 1024);     // 512 B

    prep_kernel<<<2, 256, 0, stream>>>(
        ln_k_g, ln_k_b, wk, bk, ln_q_g, ln_q_b, wq, bq, prepbuf, counts);
    proj_kernel<<<KB3 + QB3, 256, 0, stream>>>(
        grd_x, sat_x, ln_k_g, wk, ln_q_g, wq, prepbuf, kw, q);
    count_kernel<<<(B_ * M_) / 256, 256, 0, stream>>>(
        u, q, kw, grd_height, counts, bucket, out);
    battn_kernel<<<B_ * W_, 256, 0, stream>>>(
        q, kw, grd_height, counts, bucket, out);
}

// Round 6
// 146.389 us; speedup vs baseline: 1.1168x; 1.1168x over previous
//
#include <hip/hip_runtime.h>
#include <math.h>

#define B_   2
#define C_   128
#define S_   64
#define H_   128
#define W_   512
#define M_   (S_ * S_)   // 4096
#define MID_ 32
#define EPS_ 1e-5f
#define CAP_ 192         // bucket capacity; E[n]=8 (Poisson), overflow ~impossible

#define KBLK (B_ * H_ * (W_ / 64))   // 2048 k-blocks (64 positions each, 1 wave)
#define QBLK (B_ * (M_ / 64))        // 128 q-blocks

typedef __attribute__((ext_vector_type(8))) short short8;
typedef __attribute__((ext_vector_type(4))) float floatx4;

// ---------------------------------------------------------------------------
// Prep: per weight set (block 0 = k, block 1 = q):
//   1. gw = g@W, bw = b@W + bias  -> prepbuf [gw_k|bw_k|gw_q|bw_q] (32 ea)
//   2. bf16 hi/lo split of W' = diag(g)W, packed in MFMA A-fragment order:
//      idx = ((jt*4+kk)*64 + lane)*8 + i ; element = W'[kk*32+(lane>>4)*8+i][jt*16+(lane&15)]
//   3. block 0 zeroes bucket counters.
// ---------------------------------------------------------------------------
__global__ __launch_bounds__(256) void prep_kernel(
    const float* __restrict__ ln_k_g, const float* __restrict__ ln_k_b,
    const float* __restrict__ wk, const float* __restrict__ bk,
    const float* __restrict__ ln_q_g, const float* __restrict__ ln_q_b,
    const float* __restrict__ wq, const float* __restrict__ bq,
    float* __restrict__ prepbuf,
    short* __restrict__ wfrag,         // [2 sets][hi 4096 | lo 4096]
    int* __restrict__ counts)          // [B*W]
{
    const int tid = threadIdx.x;
    const int blk = blockIdx.x;        // 0: k set, 1: q set
    const float* g    = blk ? ln_q_g : ln_k_g;
    const float* bl   = blk ? ln_q_b : ln_k_b;
    const float* wt   = blk ? wq     : wk;
    const float* bias = blk ? bq     : bk;

    __shared__ float pa[256], pb[256];

    // ---- gw/bw ----
    float a = 0.f, c2 = 0.f;
#pragma unroll
    for (int k = 0; k < 16; ++k) {
        const int idx = tid + 256 * k;       // coalesced
        const float wv = wt[idx];
        const int c = idx >> 5;
        a  = fmaf(g[c],  wv, a);
        c2 = fmaf(bl[c], wv, c2);
    }
    pa[tid] = a; pb[tid] = c2;

    if (blk == 0) {                          // zero 1024 counters
        ((int4*)counts)[tid] = make_int4(0, 0, 0, 0);
    }
    __syncthreads();

    if (tid < 32) {
        float s = 0.f, t = 0.f;
#pragma unroll
        for (int r = 0; r < 8; ++r) { s += pa[tid + 32 * r]; t += pb[tid + 32 * r]; }
        prepbuf[blk * 64 + tid]      = s;
        prepbuf[blk * 64 + 32 + tid] = t + bias[tid];
    }

    // ---- bf16 hi/lo fragment tables ----
    short* whiT = wfrag + blk * 8192;
    short* wloT = whiT + 4096;
#pragma unroll
    for (int e = 0; e < 16; ++e) {
        const int idx = tid * 16 + e;
        const int i    = idx & 7;
        const int ln   = (idx >> 3) & 63;
        const int kk   = (idx >> 9) & 3;
        const int jt   = idx >> 11;
        const int c = kk * 32 + (ln >> 4) * 8 + i;
        const int j = jt * 16 + (ln & 15);
        const float wp = g[c] * wt[c * MID_ + j];
        const unsigned bbits = __float_as_uint(wp);
        const unsigned hb = bbits & 0xFFFF0000u;
        whiT[idx] = (short)(hb >> 16);
        const float r = wp - __uint_as_float(hb);
        wloT[idx] = (short)(__float_as_uint(r) >> 16);
    }
}

// ---------------------------------------------------------------------------
// Projection via bf16 hi/lo MFMA. One wave (64 threads) per 64 positions.
// A = weights (M=32 j, 2 tiles of 16), B = x (N=16 positions per tile),
// K = 128 (4 MFMA k-steps). 3 cross terms: hi*hi + hi*lo + lo*hi.
// D layout (verified): col=lane&15=pos, row=(lane>>4)*4+reg=j.
// LN stats from the same B elements via 2 shuffle-xors across quads.
// ---------------------------------------------------------------------------
__global__ __launch_bounds__(64) void proj_kernel(
    const float* __restrict__ grd_x,   // [B, C, H, W]
    const float* __restrict__ sat_x,   // [B, C, M]
    const float* __restrict__ prepbuf, // [4][32]
    const short* __restrict__ wfrag,   // [2][2][4096]
    float* __restrict__ kw,            // [B, W, H, MID]
    float* __restrict__ qv)            // [B, M, MID]
{
    const int lane = threadIdx.x;      // 0..63, one wave
    const int quad = lane >> 4;
    const int l16  = lane & 15;
    const int blk  = blockIdx.x;
    const bool is_k = (blk < KBLK);

    // geometry
    int b, h = 0, pos0;
    const float* xcol;                 // element [c=0][pos0]
    size_t xstr;
    if (is_k) {
        const int wchunk = blk & 7;
        h    = (blk >> 3) & (H_ - 1);
        b    = blk >> 10;
        pos0 = wchunk * 64;
        xcol = grd_x + ((size_t)b * C_ * H_ + h) * W_ + pos0;
        xstr = (size_t)H_ * W_;
    } else {
        const int qblk = blk - KBLK;
        b    = qblk >> 6;
        pos0 = (qblk & 63) * 64;
        xcol = sat_x + (size_t)b * C_ * M_ + pos0;
        xstr = (size_t)M_;
    }

    // ---- A-fragments (weights), pre-packed: 16+16 dwordx4 loads, L2-hot ----
    const short* whiT = wfrag + (is_k ? 0 : 8192);
    const short* wloT = whiT + 4096;
    short8 ahi[2][4], alo[2][4];
#pragma unroll
    for (int jt = 0; jt < 2; ++jt)
#pragma unroll
        for (int kk = 0; kk < 4; ++kk) {
            const int off = ((jt * 4 + kk) * 64 + lane) * 8;
            ahi[jt][kk] = *(const short8*)(whiT + off);
            alo[jt][kk] = *(const short8*)(wloT + off);
        }

    // gw/bw for this lane's output rows (j = quad*4+r, jt*16+quad*4+r)
    const int setoff = is_k ? 0 : 64;
    const float4 gw0 = *(const float4*)(prepbuf + setoff + quad * 4);
    const float4 bw0 = *(const float4*)(prepbuf + setoff + 32 + quad * 4);
    const float4 gw1 = *(const float4*)(prepbuf + setoff + 16 + quad * 4);
    const float4 bw1 = *(const float4*)(prepbuf + setoff + 48 + quad * 4);

    // ---- 4 position-tiles of 16 ----
#pragma unroll
    for (int pt = 0; pt < 4; ++pt) {
        // load this tile's B elements: x[c = kk*32+quad*8+i][pos = pt*16+l16]
        const float* xp = xcol + (size_t)(quad * 8) * xstr + pt * 16 + l16;
        float xv[32];
#pragma unroll
        for (int kk = 0; kk < 4; ++kk)
#pragma unroll
            for (int i = 0; i < 8; ++i)
                xv[kk * 8 + i] = xp[(size_t)(kk * 32 + i) * xstr];

        floatx4 acc0 = {0.f, 0.f, 0.f, 0.f};
        floatx4 acc1 = {0.f, 0.f, 0.f, 0.f};
        float p1 = 0.f, p2 = 0.f;

#pragma unroll
        for (int kk = 0; kk < 4; ++kk) {
            union { short8 v; unsigned u[4]; } bhi, blo;
#pragma unroll
            for (int e = 0; e < 4; ++e) {
                const float x0 = xv[kk * 8 + 2 * e];
                const float x1 = xv[kk * 8 + 2 * e + 1];
                p1 += x0 + x1;
                p2 = fmaf(x0, x0, p2);
                p2 = fmaf(x1, x1, p2);
                const unsigned b0 = __float_as_uint(x0);
                const unsigned b1 = __float_as_uint(x1);
                bhi.u[e] = (b1 & 0xFFFF0000u) | (b0 >> 16);
                const float r0 = x0 - __uint_as_float(b0 & 0xFFFF0000u);
                const float r1 = x1 - __uint_as_float(b1 & 0xFFFF0000u);
                blo.u[e] = (__float_as_uint(r1) & 0xFFFF0000u) |
                           (__float_as_uint(r0) >> 16);
            }
            acc0 = __builtin_amdgcn_mfma_f32_16x16x32_bf16(ahi[0][kk], bhi.v, acc0, 0, 0, 0);
            acc1 = __builtin_amdgcn_mfma_f32_16x16x32_bf16(ahi[1][kk], bhi.v, acc1, 0, 0, 0);
            acc0 = __builtin_amdgcn_mfma_f32_16x16x32_bf16(ahi[0][kk], blo.v, acc0, 0, 0, 0);
            acc1 = __builtin_amdgcn_mfma_f32_16x16x32_bf16(ahi[1][kk], blo.v, acc1, 0, 0, 0);
            acc0 = __builtin_amdgcn_mfma_f32_16x16x32_bf16(alo[0][kk], bhi.v, acc0, 0, 0, 0);
            acc1 = __builtin_amdgcn_mfma_f32_16x16x32_bf16(alo[1][kk], bhi.v, acc1, 0, 0, 0);
        }

        // LN stats for pos = pt*16+l16: reduce over the 4 quads (c-chunks)
        p1 += __shfl_xor(p1, 16, 64);
        p1 += __shfl_xor(p1, 32, 64);
        p2 += __shfl_xor(p2, 16, 64);
        p2 += __shfl_xor(p2, 32, 64);
        const float mean = p1 * (1.f / C_);
        const float rstd = rsqrtf(fmaf(-mean, mean, p2 * (1.f / C_)) + EPS_);

        // epilogue: lane holds D[j = (jt*16)+quad*4+r][pos = pt*16+l16]
        const int pos = pos0 + pt * 16 + l16;
        float* orow;
        if (is_k) orow = kw + (((size_t)b * W_ + pos) * H_ + h) * MID_;
        else      orow = qv + ((size_t)b * M_ + pos) * MID_;

        orow[quad * 4 + 0]      = fmaf(rstd, fmaf(-mean, gw0.x, acc0[0]), bw0.x);
        orow[quad * 4 + 1]      = fmaf(rstd, fmaf(-mean, gw0.y, acc0[1]), bw0.y);
        orow[quad * 4 + 2]      = fmaf(rstd, fmaf(-mean, gw0.z, acc0[2]), bw0.z);
        orow[quad * 4 + 3]      = fmaf(rstd, fmaf(-mean, gw0.w, acc0[3]), bw0.w);
        orow[16 + quad * 4 + 0] = fmaf(rstd, fmaf(-mean, gw1.x, acc1[0]), bw1.x);
        orow[16 + quad * 4 + 1] = fmaf(rstd, fmaf(-mean, gw1.y, acc1[1]), bw1.y);
        orow[16 + quad * 4 + 2] = fmaf(rstd, fmaf(-mean, gw1.z, acc1[2]), bw1.z);
        orow[16 + quad * 4 + 3] = fmaf(rstd, fmaf(-mean, gw1.w, acc1[3]), bw1.w);
    }
}

// ---------------------------------------------------------------------------
// Bucket build (runs AFTER proj so the overflow fallback is safe).
// ---------------------------------------------------------------------------
__global__ __launch_bounds__(256) void count_kernel(
    const int*   __restrict__ u,       // [B, M]
    const float* __restrict__ qv,      // [B, M, MID]  (fallback only)
    const float* __restrict__ kw,      // [B, W, H, MID] (fallback only)
    const float* __restrict__ gh,      // [B, 1, H, W]   (fallback only)
    int* __restrict__ counts,          // [B*W]
    int* __restrict__ bucket,          // [B*W][CAP_]
    float* __restrict__ out)           // [B, M]
{
    const int bm = blockIdx.x * 256 + threadIdx.x;   // 0..8191
    const int b  = bm >> 12;
    int w = u[bm];
    w = min(max(w, 0), W_ - 1);
    const int bw  = b * W_ + w;
    const int pos = atomicAdd(&counts[bw], 1);
    if (pos < CAP_) {
        bucket[bw * CAP_ + pos] = bm;
    } else {
        // dead in practice — online-softmax scalar fallback
        const float* qr = qv + (size_t)bm * MID_;
        const float* kr = kw + (size_t)bw * H_ * MID_;
        float mx = -1e30f, s = 0.f, sv = 0.f;
        for (int h = 0; h < H_; ++h) {
            float d = 0.f;
            for (int j = 0; j < MID_; ++j) d = fmaf(qr[j], kr[h * MID_ + j], d);
            d *= 0.17677669529663687f;
            const float nm   = fmaxf(mx, d);
            const float corr = __expf(mx - nm);
            const float e    = __expf(d - nm);
            s  = fmaf(s,  corr, e);
            sv = fmaf(sv, corr, e * gh[((size_t)b * H_ + h) * W_ + w]);
            mx = nm;
        }
        out[bm] = sv / s;
    }
}

// ---------------------------------------------------------------------------
// Bucketed attention: block per (b,w); each wave hoists its k fragment and
// v values ONCE, then loops over the bucket's m's (q via s_load + shuffles).
// ---------------------------------------------------------------------------
__global__ __launch_bounds__(256) void battn_kernel(
    const float* __restrict__ qv,      // [B, M, MID]
    const float* __restrict__ kw,      // [B, W, H, MID]
    const float* __restrict__ gh,      // [B, 1, H, W]
    const int*   __restrict__ counts,  // [B*W]
    const int*   __restrict__ bucket,  // [B*W][CAP_]
    float* __restrict__ out)           // [B, M]
{
    const int blk = blockIdx.x;                      // b*W + w
    const int n   = min(counts[blk], CAP_);
    const int tid  = threadIdx.x;
    const int lane = tid & 63;
    const int wv   = __builtin_amdgcn_readfirstlane(tid >> 6);
    if (wv >= n) return;                             // wave-uniform exit

    const int b = blk >> 9;
    const int w = blk & (W_ - 1);

    const float4* k4 = (const float4*)(kw + (size_t)blk * H_ * MID_);
    float4 ka[8], kb[8];
#pragma unroll
    for (int j = 0; j < 8; ++j) ka[j] = k4[lane * 8 + j];
#pragma unroll
    for (int j = 0; j < 8; ++j) kb[j] = k4[(lane + 64) * 8 + j];

    const float v0 = gh[((size_t)b * H_ + lane) * W_ + w];
    const float v1 = gh[((size_t)b * H_ + lane + 64) * W_ + w];

    const int* bkt = bucket + (size_t)blk * CAP_;
    const float sc = 0.17677669529663687f;           // 32^-0.5

    for (int i = wv; i < n; i += 4) {
        const int bm = bkt[i];                       // wave-uniform -> s_load
        const float* qr = qv + (size_t)bm * MID_;    // uniform -> s_load
        float sq[MID_];
#pragma unroll
        for (int j = 0; j < MID_; ++j) sq[j] = qr[j];

        float d0 = 0.f, d1 = 0.f;
#pragma unroll
        for (int j = 0; j < 8; ++j) {
            d0 = fmaf(sq[j * 4 + 0], ka[j].x, d0);
            d0 = fmaf(sq[j * 4 + 1], ka[j].y, d0);
            d0 = fmaf(sq[j * 4 + 2], ka[j].z, d0);
            d0 = fmaf(sq[j * 4 + 3], ka[j].w, d0);
            d1 = fmaf(sq[j * 4 + 0], kb[j].x, d1);
            d1 = fmaf(sq[j * 4 + 1], kb[j].y, d1);
            d1 = fmaf(sq[j * 4 + 2], kb[j].z, d1);
            d1 = fmaf(sq[j * 4 + 3], kb[j].w, d1);
        }
        d0 *= sc; d1 *= sc;

        float mx = fmaxf(d0, d1);
#pragma unroll
        for (int o = 32; o > 0; o >>= 1) mx = fmaxf(mx, __shfl_xor(mx, o, 64));

        const float e0 = __expf(d0 - mx);
        const float e1 = __expf(d1 - mx);
        float s   = e0 + e1;
        float svv = fmaf(e0, v0, e1 * v1);
#pragma unroll
        for (int o = 32; o > 0; o >>= 1) {
            s   += __shfl_xor(s,   o, 64);
            svv += __shfl_xor(svv, o, 64);
        }

        if (lane == 0) out[bm] = svv / s;
    }
}

// ---------------------------------------------------------------------------
extern "C" void kernel_launch(void* const* d_in, const int* in_sizes, int n_in,
                              void* d_out, int out_size, void* d_ws, size_t ws_size,
                              hipStream_t stream) {
    const float* sat_x      = (const float*)d_in[0];
    const float* grd_x      = (const float*)d_in[1];
    const float* grd_height = (const float*)d_in[2];
    const int*   u          = (const int*)d_in[3];
    const float* ln_q_g     = (const float*)d_in[4];
    const float* ln_q_b     = (const float*)d_in[5];
    const float* wq         = (const float*)d_in[6];
    const float* bq         = (const float*)d_in[7];
    const float* ln_k_g     = (const float*)d_in[8];
    const float* ln_k_b     = (const float*)d_in[9];
    const float* wk         = (const float*)d_in[10];
    const float* bk         = (const float*)d_in[11];

    float* out = (float*)d_out;

    // workspace layout
    char* ws = (char*)d_ws;
    float* kw      = (float*)ws;                                  // 16 MB
    float* q       = (float*)(ws + (size_t)16 * 1024 * 1024);     // 1 MB
    int*   counts  = (int*)  (ws + (size_t)17 * 1024 * 1024);     // 4 KB
    int*   bucket  = counts + B_ * W_;                            // 768 KB
    float* prepbuf = (float*)(ws + (size_t)18 * 1024 * 1024);     // 512 B
    short* wfrag   = (short*)(ws + (size_t)18 * 1024 * 1024 + 4096); // 32 KB

    prep_kernel<<<2, 256, 0, stream>>>(
        ln_k_g, ln_k_b, wk, bk, ln_q_g, ln_q_b, wq, bq, prepbuf, wfrag, counts);
    proj_kernel<<<KBLK + QBLK, 64, 0, stream>>>(
        grd_x, sat_x, prepbuf, wfrag, kw, q);
    count_kernel<<<(B_ * M_) / 256, 256, 0, stream>>>(
        u, q, kw, grd_height, counts, bucket, out);
    battn_kernel<<<B_ * W_, 256, 0, stream>>>(
        q, kw, grd_height, counts, bucket, out);
}

// Round 7
// 144.575 us; speedup vs baseline: 1.1308x; 1.0125x over previous
//
#include <hip/hip_runtime.h>
#include <math.h>

#define B_   2
#define C_   128
#define S_   64
#define H_   128
#define W_   512
#define M_   (S_ * S_)   // 4096
#define MID_ 32
#define EPS_ 1e-5f
#define CAP_ 192         // bucket capacity; E[n]=8 (Poisson), overflow ~impossible

#define KBLK (B_ * H_ * (W_ / 64))   // 2048 k-blocks (64 positions, 4 waves x 16)
#define QBLK (B_ * (M_ / 64))        // 128 q-blocks
#define OBLK 4                       // battn overflow tail blocks

typedef __attribute__((ext_vector_type(8))) short short8;
typedef __attribute__((ext_vector_type(4))) float floatx4;

// ---------------------------------------------------------------------------
// Prep: per weight set (block 0 = k, block 1 = q):
//   1. gw = g@W, bw = b@W + bias  -> prepbuf [gw_k|bw_k|gw_q|bw_q] (32 ea)
//   2. bf16 hi/lo split of W' = diag(g)W, packed in MFMA A-fragment order.
//   3. block 0 zeroes bucket counters + overflow counter.
// ---------------------------------------------------------------------------
__global__ __launch_bounds__(256) void prep_kernel(
    const float* __restrict__ ln_k_g, const float* __restrict__ ln_k_b,
    const float* __restrict__ wk, const float* __restrict__ bk,
    const float* __restrict__ ln_q_g, const float* __restrict__ ln_q_b,
    const float* __restrict__ wq, const float* __restrict__ bq,
    float* __restrict__ prepbuf,
    short* __restrict__ wfrag,         // [2 sets][hi 4096 | lo 4096]
    int* __restrict__ counts,          // [B*W]
    int* __restrict__ ocount)          // [1]
{
    const int tid = threadIdx.x;
    const int blk = blockIdx.x;        // 0: k set, 1: q set
    const float* g    = blk ? ln_q_g : ln_k_g;
    const float* bl   = blk ? ln_q_b : ln_k_b;
    const float* wt   = blk ? wq     : wk;
    const float* bias = blk ? bq     : bk;

    __shared__ float pa[256], pb[256];

    // ---- gw/bw ----
    float a = 0.f, c2 = 0.f;
#pragma unroll
    for (int k = 0; k < 16; ++k) {
        const int idx = tid + 256 * k;       // coalesced
        const float wv = wt[idx];
        const int c = idx >> 5;
        a  = fmaf(g[c],  wv, a);
        c2 = fmaf(bl[c], wv, c2);
    }
    pa[tid] = a; pb[tid] = c2;

    if (blk == 0) {                          // zero 1024 counters + ocount
        ((int4*)counts)[tid] = make_int4(0, 0, 0, 0);
        if (tid == 0) *ocount = 0;
    }
    __syncthreads();

    if (tid < 32) {
        float s = 0.f, t = 0.f;
#pragma unroll
        for (int r = 0; r < 8; ++r) { s += pa[tid + 32 * r]; t += pb[tid + 32 * r]; }
        prepbuf[blk * 64 + tid]      = s;
        prepbuf[blk * 64 + 32 + tid] = t + bias[tid];
    }

    // ---- bf16 hi/lo fragment tables ----
    short* whiT = wfrag + blk * 8192;
    short* wloT = whiT + 4096;
#pragma unroll
    for (int e = 0; e < 16; ++e) {
        const int idx = tid * 16 + e;
        const int i    = idx & 7;
        const int ln   = (idx >> 3) & 63;
        const int kk   = (idx >> 9) & 3;
        const int jt   = idx >> 11;
        const int c = kk * 32 + (ln >> 4) * 8 + i;
        const int j = jt * 16 + (ln & 15);
        const float wp = g[c] * wt[c * MID_ + j];
        const unsigned bbits = __float_as_uint(wp);
        const unsigned hb = bbits & 0xFFFF0000u;
        whiT[idx] = (short)(hb >> 16);
        const float r = wp - __uint_as_float(hb);
        wloT[idx] = (short)(__float_as_uint(r) >> 16);
    }
}

// ---------------------------------------------------------------------------
// Projection via bf16 hi/lo MFMA. Block = 4 waves; wave wv owns the 16-pos
// tile pt=wv (R6 had 1 wave x 4 serial tiles -> 2.1 waves/SIMD, latency-
// bound; this is 4x the wave parallelism, same total work).
// q-path additionally scatters bm into buckets (count_kernel fused here);
// overflow goes to olist, processed by battn tail blocks (kw complete then).
// ---------------------------------------------------------------------------
__global__ __launch_bounds__(256) void proj_kernel(
    const float* __restrict__ grd_x,   // [B, C, H, W]
    const float* __restrict__ sat_x,   // [B, C, M]
    const float* __restrict__ prepbuf, // [4][32]
    const short* __restrict__ wfrag,   // [2][2][4096]
    const int*   __restrict__ u,       // [B, M]
    float* __restrict__ kw,            // [B, W, H, MID]
    float* __restrict__ qv,            // [B, M, MID]
    int* __restrict__ counts,          // [B*W]
    int* __restrict__ bucket,          // [B*W][CAP_]
    int* __restrict__ ocount,          // [1]
    int* __restrict__ olist)           // [B*M]
{
    const int tid  = threadIdx.x;
    const int lane = tid & 63;
    const int wv   = __builtin_amdgcn_readfirstlane(tid >> 6);  // tile index
    const int quad = lane >> 4;
    const int l16  = lane & 15;
    const int blk  = blockIdx.x;
    const bool is_k = (blk < KBLK);

    // geometry
    int b, h = 0, pos0;
    const float* xcol;                 // element [c=0][pos0]
    size_t xstr;
    if (is_k) {
        const int wchunk = blk & 7;
        h    = (blk >> 3) & (H_ - 1);
        b    = blk >> 10;
        pos0 = wchunk * 64;
        xcol = grd_x + ((size_t)b * C_ * H_ + h) * W_ + pos0;
        xstr = (size_t)H_ * W_;
    } else {
        const int qblk = blk - KBLK;
        b    = qblk >> 6;
        pos0 = (qblk & 63) * 64;
        xcol = sat_x + (size_t)b * C_ * M_ + pos0;
        xstr = (size_t)M_;
    }
    const int pos = pos0 + wv * 16 + l16;

    // ---- B elements first (HBM, longest latency): x[c=kk*32+quad*8+i][pos]
    const float* xp = xcol + (size_t)(quad * 8) * xstr + wv * 16 + l16;
    float xv[32];
#pragma unroll
    for (int kk = 0; kk < 4; ++kk)
#pragma unroll
        for (int i = 0; i < 8; ++i)
            xv[kk * 8 + i] = xp[(size_t)(kk * 32 + i) * xstr];

    // ---- A-fragments (weights), pre-packed, L1/L2-hot ----
    const short* whiT = wfrag + (is_k ? 0 : 8192);
    const short* wloT = whiT + 4096;
    short8 ahi[2][4], alo[2][4];
#pragma unroll
    for (int jt = 0; jt < 2; ++jt)
#pragma unroll
        for (int kk = 0; kk < 4; ++kk) {
            const int off = ((jt * 4 + kk) * 64 + lane) * 8;
            ahi[jt][kk] = *(const short8*)(whiT + off);
            alo[jt][kk] = *(const short8*)(wloT + off);
        }

    // gw/bw for this lane's output rows
    const int setoff = is_k ? 0 : 64;
    const float4 gw0 = *(const float4*)(prepbuf + setoff + quad * 4);
    const float4 bw0 = *(const float4*)(prepbuf + setoff + 32 + quad * 4);
    const float4 gw1 = *(const float4*)(prepbuf + setoff + 16 + quad * 4);
    const float4 bw1 = *(const float4*)(prepbuf + setoff + 48 + quad * 4);

    floatx4 acc0 = {0.f, 0.f, 0.f, 0.f};
    floatx4 acc1 = {0.f, 0.f, 0.f, 0.f};
    float p1 = 0.f, p2 = 0.f;

#pragma unroll
    for (int kk = 0; kk < 4; ++kk) {
        union { short8 v; unsigned u[4]; } bhi, blo;
#pragma unroll
        for (int e = 0; e < 4; ++e) {
            const float x0 = xv[kk * 8 + 2 * e];
            const float x1 = xv[kk * 8 + 2 * e + 1];
            p1 += x0 + x1;
            p2 = fmaf(x0, x0, p2);
            p2 = fmaf(x1, x1, p2);
            const unsigned b0 = __float_as_uint(x0);
            const unsigned b1 = __float_as_uint(x1);
            bhi.u[e] = (b1 & 0xFFFF0000u) | (b0 >> 16);
            const float r0 = x0 - __uint_as_float(b0 & 0xFFFF0000u);
            const float r1 = x1 - __uint_as_float(b1 & 0xFFFF0000u);
            blo.u[e] = (__float_as_uint(r1) & 0xFFFF0000u) |
                       (__float_as_uint(r0) >> 16);
        }
        acc0 = __builtin_amdgcn_mfma_f32_16x16x32_bf16(ahi[0][kk], bhi.v, acc0, 0, 0, 0);
        acc1 = __builtin_amdgcn_mfma_f32_16x16x32_bf16(ahi[1][kk], bhi.v, acc1, 0, 0, 0);
        acc0 = __builtin_amdgcn_mfma_f32_16x16x32_bf16(ahi[0][kk], blo.v, acc0, 0, 0, 0);
        acc1 = __builtin_amdgcn_mfma_f32_16x16x32_bf16(ahi[1][kk], blo.v, acc1, 0, 0, 0);
        acc0 = __builtin_amdgcn_mfma_f32_16x16x32_bf16(alo[0][kk], bhi.v, acc0, 0, 0, 0);
        acc1 = __builtin_amdgcn_mfma_f32_16x16x32_bf16(alo[1][kk], bhi.v, acc1, 0, 0, 0);
    }

    // LN stats for this pos: reduce over the 4 quads (c-chunks)
    p1 += __shfl_xor(p1, 16, 64);
    p1 += __shfl_xor(p1, 32, 64);
    p2 += __shfl_xor(p2, 16, 64);
    p2 += __shfl_xor(p2, 32, 64);
    const float mean = p1 * (1.f / C_);
    const float rstd = rsqrtf(fmaf(-mean, mean, p2 * (1.f / C_)) + EPS_);

    // epilogue: lane holds D[j][pos], j = jt*16 + quad*4 + reg
    float* orow;
    if (is_k) orow = kw + (((size_t)b * W_ + pos) * H_ + h) * MID_;
    else      orow = qv + ((size_t)b * M_ + pos) * MID_;

    float4 o0, o1;
    o0.x = fmaf(rstd, fmaf(-mean, gw0.x, acc0[0]), bw0.x);
    o0.y = fmaf(rstd, fmaf(-mean, gw0.y, acc0[1]), bw0.y);
    o0.z = fmaf(rstd, fmaf(-mean, gw0.z, acc0[2]), bw0.z);
    o0.w = fmaf(rstd, fmaf(-mean, gw0.w, acc0[3]), bw0.w);
    o1.x = fmaf(rstd, fmaf(-mean, gw1.x, acc1[0]), bw1.x);
    o1.y = fmaf(rstd, fmaf(-mean, gw1.y, acc1[1]), bw1.y);
    o1.z = fmaf(rstd, fmaf(-mean, gw1.z, acc1[2]), bw1.z);
    o1.w = fmaf(rstd, fmaf(-mean, gw1.w, acc1[3]), bw1.w);
    *(float4*)(orow + quad * 4)      = o0;
    *(float4*)(orow + 16 + quad * 4) = o1;

    // ---- fused bucket scatter (q-path, one thread per m) ----
    if (!is_k && quad == 0) {
        const int bm = b * M_ + pos;
        int w = u[bm];
        w = min(max(w, 0), W_ - 1);
        const int bw = b * W_ + w;
        const int p = atomicAdd(&counts[bw], 1);
        if (p < CAP_) bucket[bw * CAP_ + p] = bm;
        else          olist[atomicAdd(ocount, 1)] = bm;
    }
}

// ---------------------------------------------------------------------------
// Bucketed attention: block per (b,w); each wave hoists its k fragment and
// v values ONCE, then loops over the bucket's m's. Tail blocks (>= B*W)
// process overflow entries (dead in practice) with un-hoisted loads.
// ---------------------------------------------------------------------------
__global__ __launch_bounds__(256) void battn_kernel(
    const float* __restrict__ qv,      // [B, M, MID]
    const float* __restrict__ kw,      // [B, W, H, MID]
    const float* __restrict__ gh,      // [B, 1, H, W]
    const int*   __restrict__ u,       // [B, M]
    const int*   __restrict__ counts,  // [B*W]
    const int*   __restrict__ bucket,  // [B*W][CAP_]
    const int*   __restrict__ ocount,  // [1]
    const int*   __restrict__ olist,   // [B*M]
    float* __restrict__ out)           // [B, M]
{
    const int blk  = blockIdx.x;
    const int tid  = threadIdx.x;
    const int lane = tid & 63;
    const int wv   = __builtin_amdgcn_readfirstlane(tid >> 6);
    const float sc = 0.17677669529663687f;           // 32^-0.5

    if (blk >= B_ * W_) {
        // ---- overflow tail (runs only if a bucket exceeded CAP_) ----
        const int nof = min(*ocount, B_ * M_);
        const int gwv = (blk - B_ * W_) * 4 + wv;
        for (int i = gwv; i < nof; i += OBLK * 4) {
            const int bm = olist[i];
            const int b  = bm >> 12;
            int w = u[bm];
            w = min(max(w, 0), W_ - 1);
            const float4* k4 = (const float4*)(kw + ((size_t)b * W_ + w) * H_ * MID_);
            const float* qr = qv + (size_t)bm * MID_;
            float sq[MID_];
#pragma unroll
            for (int j = 0; j < MID_; ++j) sq[j] = qr[j];
            float d0 = 0.f, d1 = 0.f;
#pragma unroll
            for (int j = 0; j < 8; ++j) {
                const float4 ka = k4[lane * 8 + j];
                const float4 kb = k4[(lane + 64) * 8 + j];
                d0 = fmaf(sq[j*4+0], ka.x, d0); d0 = fmaf(sq[j*4+1], ka.y, d0);
                d0 = fmaf(sq[j*4+2], ka.z, d0); d0 = fmaf(sq[j*4+3], ka.w, d0);
                d1 = fmaf(sq[j*4+0], kb.x, d1); d1 = fmaf(sq[j*4+1], kb.y, d1);
                d1 = fmaf(sq[j*4+2], kb.z, d1); d1 = fmaf(sq[j*4+3], kb.w, d1);
            }
            d0 *= sc; d1 *= sc;
            float mx = fmaxf(d0, d1);
#pragma unroll
            for (int o = 32; o > 0; o >>= 1) mx = fmaxf(mx, __shfl_xor(mx, o, 64));
            const float v0 = gh[((size_t)b * H_ + lane) * W_ + w];
            const float v1 = gh[((size_t)b * H_ + lane + 64) * W_ + w];
            const float e0 = __expf(d0 - mx);
            const float e1 = __expf(d1 - mx);
            float s   = e0 + e1;
            float svv = fmaf(e0, v0, e1 * v1);
#pragma unroll
            for (int o = 32; o > 0; o >>= 1) {
                s   += __shfl_xor(s,   o, 64);
                svv += __shfl_xor(svv, o, 64);
            }
            if (lane == 0) out[bm] = svv / s;
        }
        return;
    }

    const int n = min(counts[blk], CAP_);
    if (wv >= n) return;                             // wave-uniform exit

    const int b = blk >> 9;
    const int w = blk & (W_ - 1);

    const float4* k4 = (const float4*)(kw + (size_t)blk * H_ * MID_);
    float4 ka[8], kb[8];
#pragma unroll
    for (int j = 0; j < 8; ++j) ka[j] = k4[lane * 8 + j];
#pragma unroll
    for (int j = 0; j < 8; ++j) kb[j] = k4[(lane + 64) * 8 + j];

    const float v0 = gh[((size_t)b * H_ + lane) * W_ + w];
    const float v1 = gh[((size_t)b * H_ + lane + 64) * W_ + w];

    const int* bkt = bucket + (size_t)blk * CAP_;

    for (int i = wv; i < n; i += 4) {
        const int bm = bkt[i];                       // wave-uniform
        const float* qr = qv + (size_t)bm * MID_;
        float sq[MID_];
#pragma unroll
        for (int j = 0; j < MID_; ++j) sq[j] = qr[j];

        float d0 = 0.f, d1 = 0.f;
#pragma unroll
        for (int j = 0; j < 8; ++j) {
            d0 = fmaf(sq[j * 4 + 0], ka[j].x, d0);
            d0 = fmaf(sq[j * 4 + 1], ka[j].y, d0);
            d0 = fmaf(sq[j * 4 + 2], ka[j].z, d0);
            d0 = fmaf(sq[j * 4 + 3], ka[j].w, d0);
            d1 = fmaf(sq[j * 4 + 0], kb[j].x, d1);
            d1 = fmaf(sq[j * 4 + 1], kb[j].y, d1);
            d1 = fmaf(sq[j * 4 + 2], kb[j].z, d1);
            d1 = fmaf(sq[j * 4 + 3], kb[j].w, d1);
        }
        d0 *= sc; d1 *= sc;

        float mx = fmaxf(d0, d1);
#pragma unroll
        for (int o = 32; o > 0; o >>= 1) mx = fmaxf(mx, __shfl_xor(mx, o, 64));

        const float e0 = __expf(d0 - mx);
        const float e1 = __expf(d1 - mx);
        float s   = e0 + e1;
        float svv = fmaf(e0, v0, e1 * v1);
#pragma unroll
        for (int o = 32; o > 0; o >>= 1) {
            s   += __shfl_xor(s,   o, 64);
            svv += __shfl_xor(svv, o, 64);
        }

        if (lane == 0) out[bm] = svv / s;
    }
}

// ---------------------------------------------------------------------------
extern "C" void kernel_launch(void* const* d_in, const int* in_sizes, int n_in,
                              void* d_out, int out_size, void* d_ws, size_t ws_size,
                              hipStream_t stream) {
    const float* sat_x      = (const float*)d_in[0];
    const float* grd_x      = (const float*)d_in[1];
    const float* grd_height = (const float*)d_in[2];
    const int*   u          = (const int*)d_in[3];
    const float* ln_q_g     = (const float*)d_in[4];
    const float* ln_q_b     = (const float*)d_in[5];
    const float* wq         = (const float*)d_in[6];
    const float* bq         = (const float*)d_in[7];
    const float* ln_k_g     = (const float*)d_in[8];
    const float* ln_k_b     = (const float*)d_in[9];
    const float* wk         = (const float*)d_in[10];
    const float* bk         = (const float*)d_in[11];

    float* out = (float*)d_out;

    // workspace layout
    char* ws = (char*)d_ws;
    float* kw      = (float*)ws;                                      // 16 MB
    float* q       = (float*)(ws + (size_t)16 * 1024 * 1024);         // 1 MB
    int*   counts  = (int*)  (ws + (size_t)17 * 1024 * 1024);         // 4 KB
    int*   ocount  = (int*)  (ws + (size_t)17 * 1024 * 1024 + 4096);  // 4 KB pad
    int*   bucket  = (int*)  (ws + (size_t)17 * 1024 * 1024 + 8192);  // 768 KB
    int*   olist   = bucket + B_ * W_ * CAP_;                          // 32 KB
    float* prepbuf = (float*)(ws + (size_t)18 * 1024 * 1024);         // 512 B
    short* wfrag   = (short*)(ws + (size_t)18 * 1024 * 1024 + 4096);  // 32 KB

    prep_kernel<<<2, 256, 0, stream>>>(
        ln_k_g, ln_k_b, wk, bk, ln_q_g, ln_q_b, wq, bq,
        prepbuf, wfrag, counts, ocount);
    proj_kernel<<<KBLK + QBLK, 256, 0, stream>>>(
        grd_x, sat_x, prepbuf, wfrag, u, kw, q, counts, bucket, ocount, olist);
    battn_kernel<<<B_ * W_ + OBLK, 256, 0, stream>>>(
        q, kw, grd_height, u, counts, bucket, ocount, olist, out);
}

// Round 8
// 136.403 us; speedup vs baseline: 1.1986x; 1.0599x over previous
//
#include <hip/hip_runtime.h>
#include <math.h>

#define B_   2
#define C_   128
#define S_   64
#define H_   128
#define W_   512
#define M_   (S_ * S_)   // 4096
#define MID_ 32
#define EPS_ 1e-5f
#define CAP_ 192         // bucket capacity; E[n]=8 (Poisson), overflow ~impossible

#define KBLK (B_ * H_ * (W_ / 64))   // 2048 k-blocks (64 positions, 4 waves x 16)
#define QBLK (B_ * (M_ / 64))        // 128 q-blocks
#define OBLK 4                       // battn overflow tail blocks
#define XPAD 66                      // LDS row pitch for x-tile (64 pos + 2)

typedef __attribute__((ext_vector_type(8))) short short8;
typedef __attribute__((ext_vector_type(4))) float floatx4;

// ---------------------------------------------------------------------------
// Prep: per weight set (block 0 = k, block 1 = q):
//   1. gw = g@W, bw = b@W + bias  -> prepbuf [gw_k|bw_k|gw_q|bw_q] (32 ea)
//   2. bf16 hi/lo split of W' = diag(g)W, packed in MFMA A-fragment order.
//   3. block 0 zeroes bucket counters + overflow counter.
// ---------------------------------------------------------------------------
__global__ __launch_bounds__(256) void prep_kernel(
    const float* __restrict__ ln_k_g, const float* __restrict__ ln_k_b,
    const float* __restrict__ wk, const float* __restrict__ bk,
    const float* __restrict__ ln_q_g, const float* __restrict__ ln_q_b,
    const float* __restrict__ wq, const float* __restrict__ bq,
    float* __restrict__ prepbuf,
    short* __restrict__ wfrag,         // [2 sets][hi 4096 | lo 4096]
    int* __restrict__ counts,          // [B*W]
    int* __restrict__ ocount)          // [1]
{
    const int tid = threadIdx.x;
    const int blk = blockIdx.x;        // 0: k set, 1: q set
    const float* g    = blk ? ln_q_g : ln_k_g;
    const float* bl   = blk ? ln_q_b : ln_k_b;
    const float* wt   = blk ? wq     : wk;
    const float* bias = blk ? bq     : bk;

    __shared__ float pa[256], pb[256];

    // ---- gw/bw ----
    float a = 0.f, c2 = 0.f;
#pragma unroll
    for (int k = 0; k < 16; ++k) {
        const int idx = tid + 256 * k;       // coalesced
        const float wv = wt[idx];
        const int c = idx >> 5;
        a  = fmaf(g[c],  wv, a);
        c2 = fmaf(bl[c], wv, c2);
    }
    pa[tid] = a; pb[tid] = c2;

    if (blk == 0) {                          // zero 1024 counters + ocount
        ((int4*)counts)[tid] = make_int4(0, 0, 0, 0);
        if (tid == 0) *ocount = 0;
    }
    __syncthreads();

    if (tid < 32) {
        float s = 0.f, t = 0.f;
#pragma unroll
        for (int r = 0; r < 8; ++r) { s += pa[tid + 32 * r]; t += pb[tid + 32 * r]; }
        prepbuf[blk * 64 + tid]      = s;
        prepbuf[blk * 64 + 32 + tid] = t + bias[tid];
    }

    // ---- bf16 hi/lo fragment tables ----
    short* whiT = wfrag + blk * 8192;
    short* wloT = whiT + 4096;
#pragma unroll
    for (int e = 0; e < 16; ++e) {
        const int idx = tid * 16 + e;
        const int i    = idx & 7;
        const int ln   = (idx >> 3) & 63;
        const int kk   = (idx >> 9) & 3;
        const int jt   = idx >> 11;
        const int c = kk * 32 + (ln >> 4) * 8 + i;
        const int j = jt * 16 + (ln & 15);
        const float wp = g[c] * wt[c * MID_ + j];
        const unsigned bbits = __float_as_uint(wp);
        const unsigned hb = bbits & 0xFFFF0000u;
        whiT[idx] = (short)(hb >> 16);
        const float r = wp - __uint_as_float(hb);
        wloT[idx] = (short)(__float_as_uint(r) >> 16);
    }
}

// ---------------------------------------------------------------------------
// Projection via bf16 hi/lo MFMA with LDS-staged x-tile.
// Block = 256 threads = 4 waves; the block stages x[128c][64pos] into LDS
// with fully-coalesced dwordx4 loads (8 per thread, 4x256B segments/inst —
// R7 used 32 scalar dword loads/lane = 4x the VMEM issue work).
// Wave wv then feeds its 16-pos tile from LDS (b32 reads, 2-way = free).
// q-path scatters bm into buckets (fused count).
// ---------------------------------------------------------------------------
__global__ __launch_bounds__(256) void proj_kernel(
    const float* __restrict__ grd_x,   // [B, C, H, W]
    const float* __restrict__ sat_x,   // [B, C, M]
    const float* __restrict__ prepbuf, // [4][32]
    const short* __restrict__ wfrag,   // [2][2][4096]
    const int*   __restrict__ u,       // [B, M]
    float* __restrict__ kw,            // [B, W, H, MID]
    float* __restrict__ qv,            // [B, M, MID]
    int* __restrict__ counts,          // [B*W]
    int* __restrict__ bucket,          // [B*W][CAP_]
    int* __restrict__ ocount,          // [1]
    int* __restrict__ olist)           // [B*M]
{
    __shared__ float xs[C_ * XPAD];    // 33792 B

    const int tid  = threadIdx.x;
    const int lane = tid & 63;
    const int wv   = __builtin_amdgcn_readfirstlane(tid >> 6);  // tile index
    const int quad = lane >> 4;
    const int l16  = lane & 15;
    const int blk  = blockIdx.x;
    const bool is_k = (blk < KBLK);

    // geometry
    int b, h = 0, pos0;
    const float* xcol;                 // element [c=0][pos0]
    size_t xstr;
    if (is_k) {
        const int wchunk = blk & 7;
        h    = (blk >> 3) & (H_ - 1);
        b    = blk >> 10;
        pos0 = wchunk * 64;
        xcol = grd_x + ((size_t)b * C_ * H_ + h) * W_ + pos0;
        xstr = (size_t)H_ * W_;
    } else {
        const int qblk = blk - KBLK;
        b    = qblk >> 6;
        pos0 = (qblk & 63) * 64;
        xcol = sat_x + (size_t)b * C_ * M_ + pos0;
        xstr = (size_t)M_;
    }
    const int pos = pos0 + wv * 16 + l16;

    // ---- issue coalesced staging loads: thread -> (c = r*16 + tid>>4, 4 pos)
    const int crow0 = tid >> 4;        // 0..15
    const int pofs  = (tid & 15) * 4;  // 0..60
    float4 stg[8];
#pragma unroll
    for (int r = 0; r < 8; ++r)
        stg[r] = *(const float4*)(xcol + (size_t)(r * 16 + crow0) * xstr + pofs);

    // ---- A-fragments (weights), pre-packed, L1/L2-hot (overlap with stores)
    const short* whiT = wfrag + (is_k ? 0 : 8192);
    const short* wloT = whiT + 4096;
    short8 ahi[2][4], alo[2][4];
#pragma unroll
    for (int jt = 0; jt < 2; ++jt)
#pragma unroll
        for (int kk = 0; kk < 4; ++kk) {
            const int off = ((jt * 4 + kk) * 64 + lane) * 8;
            ahi[jt][kk] = *(const short8*)(whiT + off);
            alo[jt][kk] = *(const short8*)(wloT + off);
        }

    // ---- LDS stores (b64 pairs; [c][XPAD=66] layout) ----
#pragma unroll
    for (int r = 0; r < 8; ++r) {
        float* dst = xs + (r * 16 + crow0) * XPAD + pofs;
        *(float2*)(dst)     = make_float2(stg[r].x, stg[r].y);
        *(float2*)(dst + 2) = make_float2(stg[r].z, stg[r].w);
    }
    __syncthreads();

    // gw/bw for this lane's output rows
    const int setoff = is_k ? 0 : 64;
    const float4 gw0 = *(const float4*)(prepbuf + setoff + quad * 4);
    const float4 bw0 = *(const float4*)(prepbuf + setoff + 32 + quad * 4);
    const float4 gw1 = *(const float4*)(prepbuf + setoff + 16 + quad * 4);
    const float4 bw1 = *(const float4*)(prepbuf + setoff + 48 + quad * 4);

    floatx4 acc0 = {0.f, 0.f, 0.f, 0.f};
    floatx4 acc1 = {0.f, 0.f, 0.f, 0.f};
    float p1 = 0.f, p2 = 0.f;

    // B-fragment source: x[c = kk*32 + quad*8 + i][wv*16 + l16] from LDS
    const float* xsl = xs + quad * 8 * XPAD + wv * 16 + l16;

#pragma unroll
    for (int kk = 0; kk < 4; ++kk) {
        const float* xk = xsl + kk * 32 * XPAD;
        union { short8 v; unsigned u[4]; } bhi, blo;
#pragma unroll
        for (int e = 0; e < 4; ++e) {
            const float x0 = xk[(2 * e)     * XPAD];
            const float x1 = xk[(2 * e + 1) * XPAD];
            p1 += x0 + x1;
            p2 = fmaf(x0, x0, p2);
            p2 = fmaf(x1, x1, p2);
            const unsigned b0 = __float_as_uint(x0);
            const unsigned b1 = __float_as_uint(x1);
            bhi.u[e] = (b1 & 0xFFFF0000u) | (b0 >> 16);
            const float r0 = x0 - __uint_as_float(b0 & 0xFFFF0000u);
            const float r1 = x1 - __uint_as_float(b1 & 0xFFFF0000u);
            blo.u[e] = (__float_as_uint(r1) & 0xFFFF0000u) |
                       (__float_as_uint(r0) >> 16);
        }
        acc0 = __builtin_amdgcn_mfma_f32_16x16x32_bf16(ahi[0][kk], bhi.v, acc0, 0, 0, 0);
        acc1 = __builtin_amdgcn_mfma_f32_16x16x32_bf16(ahi[1][kk], bhi.v, acc1, 0, 0, 0);
        acc0 = __builtin_amdgcn_mfma_f32_16x16x32_bf16(ahi[0][kk], blo.v, acc0, 0, 0, 0);
        acc1 = __builtin_amdgcn_mfma_f32_16x16x32_bf16(ahi[1][kk], blo.v, acc1, 0, 0, 0);
        acc0 = __builtin_amdgcn_mfma_f32_16x16x32_bf16(alo[0][kk], bhi.v, acc0, 0, 0, 0);
        acc1 = __builtin_amdgcn_mfma_f32_16x16x32_bf16(alo[1][kk], bhi.v, acc1, 0, 0, 0);
    }

    // LN stats for this pos: reduce over the 4 quads (c-chunks)
    p1 += __shfl_xor(p1, 16, 64);
    p1 += __shfl_xor(p1, 32, 64);
    p2 += __shfl_xor(p2, 16, 64);
    p2 += __shfl_xor(p2, 32, 64);
    const float mean = p1 * (1.f / C_);
    const float rstd = rsqrtf(fmaf(-mean, mean, p2 * (1.f / C_)) + EPS_);

    // epilogue: lane holds D[j][pos], j = jt*16 + quad*4 + reg
    float* orow;
    if (is_k) orow = kw + (((size_t)b * W_ + pos) * H_ + h) * MID_;
    else      orow = qv + ((size_t)b * M_ + pos) * MID_;

    float4 o0, o1;
    o0.x = fmaf(rstd, fmaf(-mean, gw0.x, acc0[0]), bw0.x);
    o0.y = fmaf(rstd, fmaf(-mean, gw0.y, acc0[1]), bw0.y);
    o0.z = fmaf(rstd, fmaf(-mean, gw0.z, acc0[2]), bw0.z);
    o0.w = fmaf(rstd, fmaf(-mean, gw0.w, acc0[3]), bw0.w);
    o1.x = fmaf(rstd, fmaf(-mean, gw1.x, acc1[0]), bw1.x);
    o1.y = fmaf(rstd, fmaf(-mean, gw1.y, acc1[1]), bw1.y);
    o1.z = fmaf(rstd, fmaf(-mean, gw1.z, acc1[2]), bw1.z);
    o1.w = fmaf(rstd, fmaf(-mean, gw1.w, acc1[3]), bw1.w);
    *(float4*)(orow + quad * 4)      = o0;
    *(float4*)(orow + 16 + quad * 4) = o1;

    // ---- fused bucket scatter (q-path, one thread per m) ----
    if (!is_k && quad == 0) {
        const int bm = b * M_ + pos;
        int w = u[bm];
        w = min(max(w, 0), W_ - 1);
        const int bw = b * W_ + w;
        const int p = atomicAdd(&counts[bw], 1);
        if (p < CAP_) bucket[bw * CAP_ + p] = bm;
        else          olist[atomicAdd(ocount, 1)] = bm;
    }
}

// ---------------------------------------------------------------------------
// Bucketed attention: block per (b,w); each wave hoists its k fragment and
// v values ONCE, then loops over the bucket's m's. Tail blocks (>= B*W)
// process overflow entries (dead in practice) with un-hoisted loads.
// ---------------------------------------------------------------------------
__global__ __launch_bounds__(256) void battn_kernel(
    const float* __restrict__ qv,      // [B, M, MID]
    const float* __restrict__ kw,      // [B, W, H, MID]
    const float* __restrict__ gh,      // [B, 1, H, W]
    const int*   __restrict__ u,       // [B, M]
    const int*   __restrict__ counts,  // [B*W]
    const int*   __restrict__ bucket,  // [B*W][CAP_]
    const int*   __restrict__ ocount,  // [1]
    const int*   __restrict__ olist,   // [B*M]
    float* __restrict__ out)           // [B, M]
{
    const int blk  = blockIdx.x;
    const int tid  = threadIdx.x;
    const int lane = tid & 63;
    const int wv   = __builtin_amdgcn_readfirstlane(tid >> 6);
    const float sc = 0.17677669529663687f;           // 32^-0.5

    if (blk >= B_ * W_) {
        // ---- overflow tail (runs only if a bucket exceeded CAP_) ----
        const int nof = min(*ocount, B_ * M_);
        const int gwv = (blk - B_ * W_) * 4 + wv;
        for (int i = gwv; i < nof; i += OBLK * 4) {
            const int bm = olist[i];
            const int b  = bm >> 12;
            int w = u[bm];
            w = min(max(w, 0), W_ - 1);
            const float4* k4 = (const float4*)(kw + ((size_t)b * W_ + w) * H_ * MID_);
            const float* qr = qv + (size_t)bm * MID_;
            float sq[MID_];
#pragma unroll
            for (int j = 0; j < MID_; ++j) sq[j] = qr[j];
            float d0 = 0.f, d1 = 0.f;
#pragma unroll
            for (int j = 0; j < 8; ++j) {
                const float4 ka = k4[lane * 8 + j];
                const float4 kb = k4[(lane + 64) * 8 + j];
                d0 = fmaf(sq[j*4+0], ka.x, d0); d0 = fmaf(sq[j*4+1], ka.y, d0);
                d0 = fmaf(sq[j*4+2], ka.z, d0); d0 = fmaf(sq[j*4+3], ka.w, d0);
                d1 = fmaf(sq[j*4+0], kb.x, d1); d1 = fmaf(sq[j*4+1], kb.y, d1);
                d1 = fmaf(sq[j*4+2], kb.z, d1); d1 = fmaf(sq[j*4+3], kb.w, d1);
            }
            d0 *= sc; d1 *= sc;
            float mx = fmaxf(d0, d1);
#pragma unroll
            for (int o = 32; o > 0; o >>= 1) mx = fmaxf(mx, __shfl_xor(mx, o, 64));
            const float v0 = gh[((size_t)b * H_ + lane) * W_ + w];
            const float v1 = gh[((size_t)b * H_ + lane + 64) * W_ + w];
            const float e0 = __expf(d0 - mx);
            const float e1 = __expf(d1 - mx);
            float s   = e0 + e1;
            float svv = fmaf(e0, v0, e1 * v1);
#pragma unroll
            for (int o = 32; o > 0; o >>= 1) {
                s   += __shfl_xor(s,   o, 64);
                svv += __shfl_xor(svv, o, 64);
            }
            if (lane == 0) out[bm] = svv / s;
        }
        return;
    }

    const int n = min(counts[blk], CAP_);
    if (wv >= n) return;                             // wave-uniform exit

    const int b = blk >> 9;
    const int w = blk & (W_ - 1);

    const float4* k4 = (const float4*)(kw + (size_t)blk * H_ * MID_);
    float4 ka[8], kb[8];
#pragma unroll
    for (int j = 0; j < 8; ++j) ka[j] = k4[lane * 8 + j];
#pragma unroll
    for (int j = 0; j < 8; ++j) kb[j] = k4[(lane + 64) * 8 + j];

    const float v0 = gh[((size_t)b * H_ + lane) * W_ + w];
    const float v1 = gh[((size_t)b * H_ + lane + 64) * W_ + w];

    const int* bkt = bucket + (size_t)blk * CAP_;

    for (int i = wv; i < n; i += 4) {
        const int bm = bkt[i];                       // wave-uniform
        const float* qr = qv + (size_t)bm * MID_;
        float sq[MID_];
#pragma unroll
        for (int j = 0; j < MID_; ++j) sq[j] = qr[j];

        float d0 = 0.f, d1 = 0.f;
#pragma unroll
        for (int j = 0; j < 8; ++j) {
            d0 = fmaf(sq[j * 4 + 0], ka[j].x, d0);
            d0 = fmaf(sq[j * 4 + 1], ka[j].y, d0);
            d0 = fmaf(sq[j * 4 + 2], ka[j].z, d0);
            d0 = fmaf(sq[j * 4 + 3], ka[j].w, d0);
            d1 = fmaf(sq[j * 4 + 0], kb[j].x, d1);
            d1 = fmaf(sq[j * 4 + 1], kb[j].y, d1);
            d1 = fmaf(sq[j * 4 + 2], kb[j].z, d1);
            d1 = fmaf(sq[j * 4 + 3], kb[j].w, d1);
        }
        d0 *= sc; d1 *= sc;

        float mx = fmaxf(d0, d1);
#pragma unroll
        for (int o = 32; o > 0; o >>= 1) mx = fmaxf(mx, __shfl_xor(mx, o, 64));

        const float e0 = __expf(d0 - mx);
        const float e1 = __expf(d1 - mx);
        float s   = e0 + e1;
        float svv = fmaf(e0, v0, e1 * v1);
#pragma unroll
        for (int o = 32; o > 0; o >>= 1) {
            s   += __shfl_xor(s,   o, 64);
            svv += __shfl_xor(svv, o, 64);
        }

        if (lane == 0) out[bm] = svv / s;
    }
}

// ---------------------------------------------------------------------------
extern "C" void kernel_launch(void* const* d_in, const int* in_sizes, int n_in,
                              void* d_out, int out_size, void* d_ws, size_t ws_size,
                              hipStream_t stream) {
    const float* sat_x      = (const float*)d_in[0];
    const float* grd_x      = (const float*)d_in[1];
    const float* grd_height = (const float*)d_in[2];
    const int*   u          = (const int*)d_in[3];
    const float* ln_q_g     = (const float*)d_in[4];
    const float* ln_q_b     = (const float*)d_in[5];
    const float* wq         = (const float*)d_in[6];
    const float* bq         = (const float*)d_in[7];
    const float* ln_k_g     = (const float*)d_in[8];
    const float* ln_k_b     = (const float*)d_in[9];
    const float* wk         = (const float*)d_in[10];
    const float* bk         = (const float*)d_in[11];

    float* out = (float*)d_out;

    // workspace layout
    char* ws = (char*)d_ws;
    float* kw      = (float*)ws;                                      // 16 MB
    float* q       = (float*)(ws + (size_t)16 * 1024 * 1024);         // 1 MB
    int*   counts  = (int*)  (ws + (size_t)17 * 1024 * 1024);         // 4 KB
    int*   ocount  = (int*)  (ws + (size_t)17 * 1024 * 1024 + 4096);  // 4 KB pad
    int*   bucket  = (int*)  (ws + (size_t)17 * 1024 * 1024 + 8192);  // 768 KB
    int*   olist   = bucket + B_ * W_ * CAP_;                          // 32 KB
    float* prepbuf = (float*)(ws + (size_t)18 * 1024 * 1024);         // 512 B
    short* wfrag   = (short*)(ws + (size_t)18 * 1024 * 1024 + 4096);  // 32 KB

    prep_kernel<<<2, 256, 0, stream>>>(
        ln_k_g, ln_k_b, wk, bk, ln_q_g, ln_q_b, wq, bq,
        prepbuf, wfrag, counts, ocount);
    proj_kernel<<<KBLK + QBLK, 256, 0, stream>>>(
        grd_x, sat_x, prepbuf, wfrag, u, kw, q, counts, bucket, ocount, olist);
    battn_kernel<<<B_ * W_ + OBLK, 256, 0, stream>>>(
        q, kw, grd_height, u, counts, bucket, ocount, olist, out);
}

// Round 9
// 132.875 us; speedup vs baseline: 1.2304x; 1.0266x over previous
//
#include <hip/hip_runtime.h>
#include <math.h>

#define B_   2
#define C_   128
#define S_   64
#define H_   128
#define W_   512
#define M_   (S_ * S_)   // 4096
#define MID_ 32
#define EPS_ 1e-5f
#define CAP_ 192         // bucket capacity; E[n]=8 (Poisson), overflow ~impossible

#define KBLK (B_ * H_ * (W_ / 64))   // 2048 k-blocks (64 positions, 4 waves x 16)
#define QBLK (B_ * (M_ / 64))        // 128 q-blocks
#define OBLK 4                       // battn overflow tail blocks

typedef __attribute__((ext_vector_type(8))) short short8;
typedef __attribute__((ext_vector_type(4))) float floatx4;

// RNE float->bf16 pair pack (lo = a, hi = b)
__device__ __forceinline__ unsigned bfpair(float a, float b) {
    unsigned ua = __float_as_uint(a); ua += 0x7FFFu + ((ua >> 16) & 1u);
    unsigned ub = __float_as_uint(b); ub += 0x7FFFu + ((ub >> 16) & 1u);
    return (ua >> 16) | (ub & 0xFFFF0000u);
}

// ---------------------------------------------------------------------------
// Prep: per weight set (block 0 = k, block 1 = q):
//   1. gw = g@W, bw = b@W + bias  -> prepbuf [gw_k|bw_k|gw_q|bw_q] (32 ea)
//   2. bf16 hi/lo split of W' = diag(g)W, packed in MFMA A-fragment order.
//   3. block 0 zeroes bucket counters + overflow counter.
// ---------------------------------------------------------------------------
__global__ __launch_bounds__(256) void prep_kernel(
    const float* __restrict__ ln_k_g, const float* __restrict__ ln_k_b,
    const float* __restrict__ wk, const float* __restrict__ bk,
    const float* __restrict__ ln_q_g, const float* __restrict__ ln_q_b,
    const float* __restrict__ wq, const float* __restrict__ bq,
    float* __restrict__ prepbuf,
    short* __restrict__ wfrag,         // [2 sets][hi 4096 | lo 4096]
    int* __restrict__ counts,          // [B*W]
    int* __restrict__ ocount)          // [1]
{
    const int tid = threadIdx.x;
    const int blk = blockIdx.x;        // 0: k set, 1: q set
    const float* g    = blk ? ln_q_g : ln_k_g;
    const float* bl   = blk ? ln_q_b : ln_k_b;
    const float* wt   = blk ? wq     : wk;
    const float* bias = blk ? bq     : bk;

    __shared__ float pa[256], pb[256];

    // ---- gw/bw ----
    float a = 0.f, c2 = 0.f;
#pragma unroll
    for (int k = 0; k < 16; ++k) {
        const int idx = tid + 256 * k;       // coalesced
        const float wv = wt[idx];
        const int c = idx >> 5;
        a  = fmaf(g[c],  wv, a);
        c2 = fmaf(bl[c], wv, c2);
    }
    pa[tid] = a; pb[tid] = c2;

    if (blk == 0) {                          // zero 1024 counters + ocount
        ((int4*)counts)[tid] = make_int4(0, 0, 0, 0);
        if (tid == 0) *ocount = 0;
    }
    __syncthreads();

    if (tid < 32) {
        float s = 0.f, t = 0.f;
#pragma unroll
        for (int r = 0; r < 8; ++r) { s += pa[tid + 32 * r]; t += pb[tid + 32 * r]; }
        prepbuf[blk * 64 + tid]      = s;
        prepbuf[blk * 64 + 32 + tid] = t + bias[tid];
    }

    // ---- bf16 hi/lo fragment tables ----
    short* whiT = wfrag + blk * 8192;
    short* wloT = whiT + 4096;
#pragma unroll
    for (int e = 0; e < 16; ++e) {
        const int idx = tid * 16 + e;
        const int i    = idx & 7;
        const int ln   = (idx >> 3) & 63;
        const int kk   = (idx >> 9) & 3;
        const int jt   = idx >> 11;
        const int c = kk * 32 + (ln >> 4) * 8 + i;
        const int j = jt * 16 + (ln & 15);
        const float wp = g[c] * wt[c * MID_ + j];
        const unsigned bbits = __float_as_uint(wp);
        const unsigned hb = bbits & 0xFFFF0000u;
        whiT[idx] = (short)(hb >> 16);
        const float r = wp - __uint_as_float(hb);
        wloT[idx] = (short)(__float_as_uint(r) >> 16);
    }
}

// ---------------------------------------------------------------------------
// Projection via bf16 hi/lo MFMA, x staged with global_load_lds (width 16).
// Block = 4 waves; wave wv owns the 16-pos tile. LDS layout [c][64] with
// free swizzle pos^16*((c>>3)&1): wave-uniform on the DMA (applied to the
// SOURCE index, keeping lane*16 contiguity), quad&1 on reads (2-way = free).
// kw output stored bf16 (RNE). q-path scatters bm into buckets.
// ---------------------------------------------------------------------------
__global__ __launch_bounds__(256) void proj_kernel(
    const float* __restrict__ grd_x,   // [B, C, H, W]
    const float* __restrict__ sat_x,   // [B, C, M]
    const float* __restrict__ prepbuf, // [4][32]
    const short* __restrict__ wfrag,   // [2][2][4096]
    const int*   __restrict__ u,       // [B, M]
    unsigned short* __restrict__ kwb,  // [B, W, H, MID] bf16
    float* __restrict__ qv,            // [B, M, MID]
    int* __restrict__ counts,          // [B*W]
    int* __restrict__ bucket,          // [B*W][CAP_]
    int* __restrict__ ocount,          // [1]
    int* __restrict__ olist)           // [B*M]
{
    __shared__ float xs[C_ * 64];      // 32768 B -> 5 blocks/CU

    const int tid  = threadIdx.x;
    const int lane = tid & 63;
    const int wv   = __builtin_amdgcn_readfirstlane(tid >> 6);  // tile index
    const int quad = lane >> 4;
    const int l16  = lane & 15;
    const int blk  = blockIdx.x;
    const bool is_k = (blk < KBLK);

    // geometry
    int b, h = 0, pos0;
    const float* xcol;                 // element [c=0][pos0]
    size_t xstr;
    if (is_k) {
        const int wchunk = blk & 7;
        h    = (blk >> 3) & (H_ - 1);
        b    = blk >> 10;
        pos0 = wchunk * 64;
        xcol = grd_x + ((size_t)b * C_ * H_ + h) * W_ + pos0;
        xstr = (size_t)H_ * W_;
    } else {
        const int qblk = blk - KBLK;
        b    = qblk >> 6;
        pos0 = (qblk & 63) * 64;
        xcol = sat_x + (size_t)b * C_ * M_ + pos0;
        xstr = (size_t)M_;
    }
    const int pos = pos0 + wv * 16 + l16;

    // ---- DMA staging: wave wv covers c rows {16r + 4wv + (lane>>4)} ----
    // swizzle key for these c's: ((c>>3)&1) == (wv>>1), wave-uniform.
    {
        const int swz  = (wv >> 1) << 4;                 // 0 or 16 dwords
        const float* gsrc = xcol + (size_t)(lane >> 4) * xstr
                                 + (((lane & 15) * 4) ^ swz);
#pragma unroll
        for (int r = 0; r < 8; ++r) {
            const float* src = gsrc + (size_t)(r * 16 + wv * 4) * xstr;
            float* dst = xs + (r * 16 + wv * 4) * 64;    // wave-uniform base
            __builtin_amdgcn_global_load_lds(
                (const __attribute__((address_space(1))) unsigned int*)src,
                (__attribute__((address_space(3))) unsigned int*)dst,
                16, 0, 0);
        }
    }

    // ---- A-fragments (weights), pre-packed, L1/L2-hot (overlap with DMA) --
    const short* whiT = wfrag + (is_k ? 0 : 8192);
    const short* wloT = whiT + 4096;
    short8 ahi[2][4], alo[2][4];
#pragma unroll
    for (int jt = 0; jt < 2; ++jt)
#pragma unroll
        for (int kk = 0; kk < 4; ++kk) {
            const int off = ((jt * 4 + kk) * 64 + lane) * 8;
            ahi[jt][kk] = *(const short8*)(whiT + off);
            alo[jt][kk] = *(const short8*)(wloT + off);
        }

    // gw/bw for this lane's output rows
    const int setoff = is_k ? 0 : 64;
    const float4 gw0 = *(const float4*)(prepbuf + setoff + quad * 4);
    const float4 bw0 = *(const float4*)(prepbuf + setoff + 32 + quad * 4);
    const float4 gw1 = *(const float4*)(prepbuf + setoff + 16 + quad * 4);
    const float4 bw1 = *(const float4*)(prepbuf + setoff + 48 + quad * 4);

    __syncthreads();                   // drains DMA (vmcnt) + all waves

    floatx4 acc0 = {0.f, 0.f, 0.f, 0.f};
    floatx4 acc1 = {0.f, 0.f, 0.f, 0.f};
    float p1 = 0.f, p2 = 0.f;

    // B-fragment source: x[c = kk*32 + quad*8 + i][wv*16 + l16], swizzled
    const int rpos = (wv * 16 + l16) ^ ((quad & 1) << 4);
    const float* xsl = xs + quad * 8 * 64 + rpos;

#pragma unroll
    for (int kk = 0; kk < 4; ++kk) {
        const float* xk = xsl + kk * 32 * 64;
        union { short8 v; unsigned u[4]; } bhi, blo;
#pragma unroll
        for (int e = 0; e < 4; ++e) {
            const float x0 = xk[(2 * e)     * 64];
            const float x1 = xk[(2 * e + 1) * 64];
            p1 += x0 + x1;
            p2 = fmaf(x0, x0, p2);
            p2 = fmaf(x1, x1, p2);
            const unsigned b0 = __float_as_uint(x0);
            const unsigned b1 = __float_as_uint(x1);
            bhi.u[e] = (b1 & 0xFFFF0000u) | (b0 >> 16);
            const float r0 = x0 - __uint_as_float(b0 & 0xFFFF0000u);
            const float r1 = x1 - __uint_as_float(b1 & 0xFFFF0000u);
            blo.u[e] = (__float_as_uint(r1) & 0xFFFF0000u) |
                       (__float_as_uint(r0) >> 16);
        }
        acc0 = __builtin_amdgcn_mfma_f32_16x16x32_bf16(ahi[0][kk], bhi.v, acc0, 0, 0, 0);
        acc1 = __builtin_amdgcn_mfma_f32_16x16x32_bf16(ahi[1][kk], bhi.v, acc1, 0, 0, 0);
        acc0 = __builtin_amdgcn_mfma_f32_16x16x32_bf16(ahi[0][kk], blo.v, acc0, 0, 0, 0);
        acc1 = __builtin_amdgcn_mfma_f32_16x16x32_bf16(ahi[1][kk], blo.v, acc1, 0, 0, 0);
        acc0 = __builtin_amdgcn_mfma_f32_16x16x32_bf16(alo[0][kk], bhi.v, acc0, 0, 0, 0);
        acc1 = __builtin_amdgcn_mfma_f32_16x16x32_bf16(alo[1][kk], bhi.v, acc1, 0, 0, 0);
    }

    // LN stats for this pos: reduce over the 4 quads (c-chunks)
    p1 += __shfl_xor(p1, 16, 64);
    p1 += __shfl_xor(p1, 32, 64);
    p2 += __shfl_xor(p2, 16, 64);
    p2 += __shfl_xor(p2, 32, 64);
    const float mean = p1 * (1.f / C_);
    const float rstd = rsqrtf(fmaf(-mean, mean, p2 * (1.f / C_)) + EPS_);

    // epilogue: lane holds D[j][pos], j = jt*16 + quad*4 + reg
    float o0x = fmaf(rstd, fmaf(-mean, gw0.x, acc0[0]), bw0.x);
    float o0y = fmaf(rstd, fmaf(-mean, gw0.y, acc0[1]), bw0.y);
    float o0z = fmaf(rstd, fmaf(-mean, gw0.z, acc0[2]), bw0.z);
    float o0w = fmaf(rstd, fmaf(-mean, gw0.w, acc0[3]), bw0.w);
    float o1x = fmaf(rstd, fmaf(-mean, gw1.x, acc1[0]), bw1.x);
    float o1y = fmaf(rstd, fmaf(-mean, gw1.y, acc1[1]), bw1.y);
    float o1z = fmaf(rstd, fmaf(-mean, gw1.z, acc1[2]), bw1.z);
    float o1w = fmaf(rstd, fmaf(-mean, gw1.w, acc1[3]), bw1.w);

    if (is_k) {
        // bf16 store: row of 32 bf16; lane writes j0=quad*4 (+16)
        unsigned short* orow = kwb + (((size_t)b * W_ + pos) * H_ + h) * MID_;
        uint2 u0, u1;
        u0.x = bfpair(o0x, o0y); u0.y = bfpair(o0z, o0w);
        u1.x = bfpair(o1x, o1y); u1.y = bfpair(o1z, o1w);
        *(uint2*)(orow + quad * 4)      = u0;
        *(uint2*)(orow + 16 + quad * 4) = u1;
    } else {
        float* orow = qv + ((size_t)b * M_ + pos) * MID_;
        *(float4*)(orow + quad * 4)      = make_float4(o0x, o0y, o0z, o0w);
        *(float4*)(orow + 16 + quad * 4) = make_float4(o1x, o1y, o1z, o1w);
        // ---- fused bucket scatter (one thread per m) ----
        if (quad == 0) {
            const int bm = b * M_ + pos;
            int w = u[bm];
            w = min(max(w, 0), W_ - 1);
            const int bw = b * W_ + w;
            const int p = atomicAdd(&counts[bw], 1);
            if (p < CAP_) bucket[bw * CAP_ + p] = bm;
            else          olist[atomicAdd(ocount, 1)] = bm;
        }
    }
}

// ---------------------------------------------------------------------------
// Bucketed attention: block per (b,w); each wave hoists its (bf16) k row and
// v values ONCE (unpack outside the m-loop), then loops over the bucket's
// m's. Tail blocks process overflow entries (dead in practice).
// ---------------------------------------------------------------------------
__global__ __launch_bounds__(256) void battn_kernel(
    const float* __restrict__ qv,      // [B, M, MID]
    const unsigned short* __restrict__ kwb, // [B, W, H, MID] bf16
    const float* __restrict__ gh,      // [B, 1, H, W]
    const int*   __restrict__ u,       // [B, M]
    const int*   __restrict__ counts,  // [B*W]
    const int*   __restrict__ bucket,  // [B*W][CAP_]
    const int*   __restrict__ ocount,  // [1]
    const int*   __restrict__ olist,   // [B*M]
    float* __restrict__ out)           // [B, M]
{
    const int blk  = blockIdx.x;
    const int tid  = threadIdx.x;
    const int lane = tid & 63;
    const int wv   = __builtin_amdgcn_readfirstlane(tid >> 6);
    const float sc = 0.17677669529663687f;           // 32^-0.5

    if (blk >= B_ * W_) {
        // ---- overflow tail (runs only if a bucket exceeded CAP_) ----
        const int nof = min(*ocount, B_ * M_);
        const int gwv = (blk - B_ * W_) * 4 + wv;
        for (int i = gwv; i < nof; i += OBLK * 4) {
            const int bm = olist[i];
            const int b  = bm >> 12;
            int w = u[bm];
            w = min(max(w, 0), W_ - 1);
            const unsigned short* kr = kwb + ((size_t)b * W_ + w) * H_ * MID_;
            const float* qr = qv + (size_t)bm * MID_;
            float sq[MID_];
#pragma unroll
            for (int j = 0; j < MID_; ++j) sq[j] = qr[j];
            float d0 = 0.f, d1 = 0.f;
#pragma unroll
            for (int j = 0; j < MID_; ++j) {
                d0 = fmaf(sq[j], __uint_as_float((unsigned)kr[lane * MID_ + j] << 16), d0);
                d1 = fmaf(sq[j], __uint_as_float((unsigned)kr[(lane + 64) * MID_ + j] << 16), d1);
            }
            d0 *= sc; d1 *= sc;
            float mx = fmaxf(d0, d1);
#pragma unroll
            for (int o = 32; o > 0; o >>= 1) mx = fmaxf(mx, __shfl_xor(mx, o, 64));
            const float v0 = gh[((size_t)b * H_ + lane) * W_ + w];
            const float v1 = gh[((size_t)b * H_ + lane + 64) * W_ + w];
            const float e0 = __expf(d0 - mx);
            const float e1 = __expf(d1 - mx);
            float s   = e0 + e1;
            float svv = fmaf(e0, v0, e1 * v1);
#pragma unroll
            for (int o = 32; o > 0; o >>= 1) {
                s   += __shfl_xor(s,   o, 64);
                svv += __shfl_xor(svv, o, 64);
            }
            if (lane == 0) out[bm] = svv / s;
        }
        return;
    }

    const int n = min(counts[blk], CAP_);
    if (wv >= n) return;                             // wave-uniform exit

    const int b = blk >> 9;
    const int w = blk & (W_ - 1);

    // hoist + unpack k rows for h=lane and h=lane+64 (bf16 -> f32, once)
    const uint4* k4 = (const uint4*)(kwb + (size_t)blk * H_ * MID_);
    float ka[32], kb[32];
#pragma unroll
    for (int t = 0; t < 4; ++t) {
        const uint4 ua = k4[lane * 4 + t];
        const uint4 ub = k4[(lane + 64) * 4 + t];
        ka[t*8+0] = __uint_as_float(ua.x << 16); ka[t*8+1] = __uint_as_float(ua.x & 0xFFFF0000u);
        ka[t*8+2] = __uint_as_float(ua.y << 16); ka[t*8+3] = __uint_as_float(ua.y & 0xFFFF0000u);
        ka[t*8+4] = __uint_as_float(ua.z << 16); ka[t*8+5] = __uint_as_float(ua.z & 0xFFFF0000u);
        ka[t*8+6] = __uint_as_float(ua.w << 16); ka[t*8+7] = __uint_as_float(ua.w & 0xFFFF0000u);
        kb[t*8+0] = __uint_as_float(ub.x << 16); kb[t*8+1] = __uint_as_float(ub.x & 0xFFFF0000u);
        kb[t*8+2] = __uint_as_float(ub.y << 16); kb[t*8+3] = __uint_as_float(ub.y & 0xFFFF0000u);
        kb[t*8+4] = __uint_as_float(ub.z << 16); kb[t*8+5] = __uint_as_float(ub.z & 0xFFFF0000u);
        kb[t*8+6] = __uint_as_float(ub.w << 16); kb[t*8+7] = __uint_as_float(ub.w & 0xFFFF0000u);
    }

    const float v0 = gh[((size_t)b * H_ + lane) * W_ + w];
    const float v1 = gh[((size_t)b * H_ + lane + 64) * W_ + w];

    const int* bkt = bucket + (size_t)blk * CAP_;

    for (int i = wv; i < n; i += 4) {
        const int bm = bkt[i];                       // wave-uniform
        const float* qr = qv + (size_t)bm * MID_;
        float sq[MID_];
#pragma unroll
        for (int j = 0; j < MID_; ++j) sq[j] = qr[j];

        float d0 = 0.f, d1 = 0.f;
#pragma unroll
        for (int j = 0; j < MID_; ++j) {
            d0 = fmaf(sq[j], ka[j], d0);
            d1 = fmaf(sq[j], kb[j], d1);
        }
        d0 *= sc; d1 *= sc;

        float mx = fmaxf(d0, d1);
#pragma unroll
        for (int o = 32; o > 0; o >>= 1) mx = fmaxf(mx, __shfl_xor(mx, o, 64));

        const float e0 = __expf(d0 - mx);
        const float e1 = __expf(d1 - mx);
        float s   = e0 + e1;
        float svv = fmaf(e0, v0, e1 * v1);
#pragma unroll
        for (int o = 32; o > 0; o >>= 1) {
            s   += __shfl_xor(s,   o, 64);
            svv += __shfl_xor(svv, o, 64);
        }

        if (lane == 0) out[bm] = svv / s;
    }
}

// ---------------------------------------------------------------------------
extern "C" void kernel_launch(void* const* d_in, const int* in_sizes, int n_in,
                              void* d_out, int out_size, void* d_ws, size_t ws_size,
                              hipStream_t stream) {
    const float* sat_x      = (const float*)d_in[0];
    const float* grd_x      = (const float*)d_in[1];
    const float* grd_height = (const float*)d_in[2];
    const int*   u          = (const int*)d_in[3];
    const float* ln_q_g     = (const float*)d_in[4];
    const float* ln_q_b     = (const float*)d_in[5];
    const float* wq         = (const float*)d_in[6];
    const float* bq         = (const float*)d_in[7];
    const float* ln_k_g     = (const float*)d_in[8];
    const float* ln_k_b     = (const float*)d_in[9];
    const float* wk         = (const float*)d_in[10];
    const float* bk         = (const float*)d_in[11];

    float* out = (float*)d_out;

    // workspace layout
    char* ws = (char*)d_ws;
    unsigned short* kwb = (unsigned short*)ws;                        // 8 MB (bf16)
    float* q       = (float*)(ws + (size_t)8  * 1024 * 1024);         // 1 MB
    int*   counts  = (int*)  (ws + (size_t)9  * 1024 * 1024);         // 4 KB
    int*   ocount  = (int*)  (ws + (size_t)9  * 1024 * 1024 + 4096);  // 4 KB pad
    int*   bucket  = (int*)  (ws + (size_t)9  * 1024 * 1024 + 8192);  // 768 KB
    int*   olist   = bucket + B_ * W_ * CAP_;                          // 32 KB
    float* prepbuf = (float*)(ws + (size_t)10 * 1024 * 1024);         // 512 B
    short* wfrag   = (short*)(ws + (size_t)10 * 1024 * 1024 + 4096);  // 32 KB

    prep_kernel<<<2, 256, 0, stream>>>(
        ln_k_g, ln_k_b, wk, bk, ln_q_g, ln_q_b, wq, bq,
        prepbuf, wfrag, counts, ocount);
    proj_kernel<<<KBLK + QBLK, 256, 0, stream>>>(
        grd_x, sat_x, prepbuf, wfrag, u, kwb, q, counts, bucket, ocount, olist);
    battn_kernel<<<B_ * W_ + OBLK, 256, 0, stream>>>(
        q, kwb, grd_height, u, counts, bucket, ocount, olist, out);
}

// Round 11
// 130.739 us; speedup vs baseline: 1.2505x; 1.0163x over previous
//
#include <hip/hip_runtime.h>
#include <math.h>

#define B_   2
#define C_   128
#define S_   64
#define H_   128
#define W_   512
#define M_   (S_ * S_)   // 4096
#define MID_ 32
#define EPS_ 1e-5f
#define CAP_ 192         // bucket capacity; E[n]=8 (Poisson), overflow ~impossible

#define KBLK (B_ * H_ * (W_ / 64))   // 2048 k-blocks (64 positions, 4 waves x 16)
#define QBLK (B_ * (M_ / 64))        // 128 q-blocks
#define OBLK 4                       // battn overflow tail blocks

typedef __attribute__((ext_vector_type(8))) short short8;
typedef __attribute__((ext_vector_type(4))) float floatx4;

// RNE float->bf16 pair pack (lo = a, hi = b)
__device__ __forceinline__ unsigned bfpair(float a, float b) {
    unsigned ua = __float_as_uint(a); ua += 0x7FFFu + ((ua >> 16) & 1u);
    unsigned ub = __float_as_uint(b); ub += 0x7FFFu + ((ub >> 16) & 1u);
    return (ua >> 16) | (ub & 0xFFFF0000u);
}

// ---------------------------------------------------------------------------
// Prep: per weight set (block 0 = k, block 1 = q):
//   1. gw = g@W, bw = b@W + bias  -> prepbuf [gw_k|bw_k|gw_q|bw_q] (32 ea)
//   2. bf16 hi/lo split of W' = diag(g)W, packed in MFMA A-fragment order.
//   3. block 0 zeroes bucket counters + overflow counter.
// ---------------------------------------------------------------------------
__global__ __launch_bounds__(256) void prep_kernel(
    const float* __restrict__ ln_k_g, const float* __restrict__ ln_k_b,
    const float* __restrict__ wk, const float* __restrict__ bk,
    const float* __restrict__ ln_q_g, const float* __restrict__ ln_q_b,
    const float* __restrict__ wq, const float* __restrict__ bq,
    float* __restrict__ prepbuf,
    short* __restrict__ wfrag,         // [2 sets][hi 4096 | lo 4096]
    int* __restrict__ counts,          // [B*W]
    int* __restrict__ ocount)          // [1]
{
    const int tid = threadIdx.x;
    const int blk = blockIdx.x;        // 0: k set, 1: q set
    const float* g    = blk ? ln_q_g : ln_k_g;
    const float* bl   = blk ? ln_q_b : ln_k_b;
    const float* wt   = blk ? wq     : wk;
    const float* bias = blk ? bq     : bk;

    __shared__ float pa[256], pb[256];

    // ---- gw/bw ----
    float a = 0.f, c2 = 0.f;
#pragma unroll
    for (int k = 0; k < 16; ++k) {
        const int idx = tid + 256 * k;       // coalesced
        const float wv = wt[idx];
        const int c = idx >> 5;
        a  = fmaf(g[c],  wv, a);
        c2 = fmaf(bl[c], wv, c2);
    }
    pa[tid] = a; pb[tid] = c2;

    if (blk == 0) {                          // zero 1024 counters + ocount
        ((int4*)counts)[tid] = make_int4(0, 0, 0, 0);
        if (tid == 0) *ocount = 0;
    }
    __syncthreads();

    if (tid < 32) {
        float s = 0.f, t = 0.f;
#pragma unroll
        for (int r = 0; r < 8; ++r) { s += pa[tid + 32 * r]; t += pb[tid + 32 * r]; }
        prepbuf[blk * 64 + tid]      = s;
        prepbuf[blk * 64 + 32 + tid] = t + bias[tid];
    }

    // ---- bf16 hi/lo fragment tables ----
    short* whiT = wfrag + blk * 8192;
    short* wloT = whiT + 4096;
#pragma unroll
    for (int e = 0; e < 16; ++e) {
        const int idx = tid * 16 + e;
        const int i    = idx & 7;
        const int ln   = (idx >> 3) & 63;
        const int kk   = (idx >> 9) & 3;
        const int jt   = idx >> 11;
        const int c = kk * 32 + (ln >> 4) * 8 + i;
        const int j = jt * 16 + (ln & 15);
        const float wp = g[c] * wt[c * MID_ + j];
        const unsigned bbits = __float_as_uint(wp);
        const unsigned hb = bbits & 0xFFFF0000u;
        whiT[idx] = (short)(hb >> 16);
        const float r = wp - __uint_as_float(hb);
        wloT[idx] = (short)(__float_as_uint(r) >> 16);
    }
}

// ---------------------------------------------------------------------------
// Projection via bf16 hi/lo MFMA, x staged with global_load_lds (width 16).
// Block = 4 waves; wave wv owns the 16-pos tile. LDS layout [c][64] with
// free swizzle pos^16*((c>>3)&1): wave-uniform on the DMA (applied to the
// SOURCE index, keeping lane*16 contiguity), quad&1 on reads (2-way = free).
// kw output stored bf16 (RNE). q-path scatters bm into buckets.
// ---------------------------------------------------------------------------
__global__ __launch_bounds__(256) void proj_kernel(
    const float* __restrict__ grd_x,   // [B, C, H, W]
    const float* __restrict__ sat_x,   // [B, C, M]
    const float* __restrict__ prepbuf, // [4][32]
    const short* __restrict__ wfrag,   // [2][2][4096]
    const int*   __restrict__ u,       // [B, M]
    unsigned short* __restrict__ kwb,  // [B, W, H, MID] bf16
    float* __restrict__ qv,            // [B, M, MID]
    int* __restrict__ counts,          // [B*W]
    int* __restrict__ bucket,          // [B*W][CAP_]
    int* __restrict__ ocount,          // [1]
    int* __restrict__ olist)           // [B*M]
{
    __shared__ float xs[C_ * 64];      // 32768 B -> 5 blocks/CU

    const int tid  = threadIdx.x;
    const int lane = tid & 63;
    const int wv   = __builtin_amdgcn_readfirstlane(tid >> 6);  // tile index
    const int quad = lane >> 4;
    const int l16  = lane & 15;
    const int blk  = blockIdx.x;
    const bool is_k = (blk < KBLK);

    // geometry
    int b, h = 0, pos0;
    const float* xcol;                 // element [c=0][pos0]
    size_t xstr;
    if (is_k) {
        const int wchunk = blk & 7;
        h    = (blk >> 3) & (H_ - 1);
        b    = blk >> 10;
        pos0 = wchunk * 64;
        xcol = grd_x + ((size_t)b * C_ * H_ + h) * W_ + pos0;
        xstr = (size_t)H_ * W_;
    } else {
        const int qblk = blk - KBLK;
        b    = qblk >> 6;
        pos0 = (qblk & 63) * 64;
        xcol = sat_x + (size_t)b * C_ * M_ + pos0;
        xstr = (size_t)M_;
    }
    const int pos = pos0 + wv * 16 + l16;

    // ---- DMA staging: wave wv covers c rows {16r + 4wv + (lane>>4)} ----
    // swizzle key for these c's: ((c>>3)&1) == (wv>>1), wave-uniform.
    {
        const int swz  = (wv >> 1) << 4;                 // 0 or 16 dwords
        const float* gsrc = xcol + (size_t)(lane >> 4) * xstr
                                 + (((lane & 15) * 4) ^ swz);
#pragma unroll
        for (int r = 0; r < 8; ++r) {
            const float* src = gsrc + (size_t)(r * 16 + wv * 4) * xstr;
            float* dst = xs + (r * 16 + wv * 4) * 64;    // wave-uniform base
            __builtin_amdgcn_global_load_lds(
                (const __attribute__((address_space(1))) unsigned int*)src,
                (__attribute__((address_space(3))) unsigned int*)dst,
                16, 0, 0);
        }
    }

    // ---- A-fragments (weights), pre-packed, L1/L2-hot (overlap with DMA) --
    const short* whiT = wfrag + (is_k ? 0 : 8192);
    const short* wloT = whiT + 4096;
    short8 ahi[2][4], alo[2][4];
#pragma unroll
    for (int jt = 0; jt < 2; ++jt)
#pragma unroll
        for (int kk = 0; kk < 4; ++kk) {
            const int off = ((jt * 4 + kk) * 64 + lane) * 8;
            ahi[jt][kk] = *(const short8*)(whiT + off);
            alo[jt][kk] = *(const short8*)(wloT + off);
        }

    // gw/bw for this lane's output rows
    const int setoff = is_k ? 0 : 64;
    const float4 gw0 = *(const float4*)(prepbuf + setoff + quad * 4);
    const float4 bw0 = *(const float4*)(prepbuf + setoff + 32 + quad * 4);
    const float4 gw1 = *(const float4*)(prepbuf + setoff + 16 + quad * 4);
    const float4 bw1 = *(const float4*)(prepbuf + setoff + 48 + quad * 4);

    __syncthreads();                   // drains DMA (vmcnt) + all waves

    floatx4 acc0 = {0.f, 0.f, 0.f, 0.f};
    floatx4 acc1 = {0.f, 0.f, 0.f, 0.f};
    float p1 = 0.f, p2 = 0.f;

    // B-fragment source: x[c = kk*32 + quad*8 + i][wv*16 + l16], swizzled
    const int rpos = (wv * 16 + l16) ^ ((quad & 1) << 4);
    const float* xsl = xs + quad * 8 * 64 + rpos;

#pragma unroll
    for (int kk = 0; kk < 4; ++kk) {
        const float* xk = xsl + kk * 32 * 64;
        union { short8 v; unsigned u[4]; } bhi, blo;
#pragma unroll
        for (int e = 0; e < 4; ++e) {
            const float x0 = xk[(2 * e)     * 64];
            const float x1 = xk[(2 * e + 1) * 64];
            p1 += x0 + x1;
            p2 = fmaf(x0, x0, p2);
            p2 = fmaf(x1, x1, p2);
            const unsigned b0 = __float_as_uint(x0);
            const unsigned b1 = __float_as_uint(x1);
            bhi.u[e] = (b1 & 0xFFFF0000u) | (b0 >> 16);
            const float r0 = x0 - __uint_as_float(b0 & 0xFFFF0000u);
            const float r1 = x1 - __uint_as_float(b1 & 0xFFFF0000u);
            blo.u[e] = (__float_as_uint(r1) & 0xFFFF0000u) |
                       (__float_as_uint(r0) >> 16);
        }
        acc0 = __builtin_amdgcn_mfma_f32_16x16x32_bf16(ahi[0][kk], bhi.v, acc0, 0, 0, 0);
        acc1 = __builtin_amdgcn_mfma_f32_16x16x32_bf16(ahi[1][kk], bhi.v, acc1, 0, 0, 0);
        acc0 = __builtin_amdgcn_mfma_f32_16x16x32_bf16(ahi[0][kk], blo.v, acc0, 0, 0, 0);
        acc1 = __builtin_amdgcn_mfma_f32_16x16x32_bf16(ahi[1][kk], blo.v, acc1, 0, 0, 0);
        acc0 = __builtin_amdgcn_mfma_f32_16x16x32_bf16(alo[0][kk], bhi.v, acc0, 0, 0, 0);
        acc1 = __builtin_amdgcn_mfma_f32_16x16x32_bf16(alo[1][kk], bhi.v, acc1, 0, 0, 0);
    }

    // LN stats for this pos: reduce over the 4 quads (c-chunks)
    p1 += __shfl_xor(p1, 16, 64);
    p1 += __shfl_xor(p1, 32, 64);
    p2 += __shfl_xor(p2, 16, 64);
    p2 += __shfl_xor(p2, 32, 64);
    const float mean = p1 * (1.f / C_);
    const float rstd = rsqrtf(fmaf(-mean, mean, p2 * (1.f / C_)) + EPS_);

    // epilogue: lane holds D[j][pos], j = jt*16 + quad*4 + reg
    float o0x = fmaf(rstd, fmaf(-mean, gw0.x, acc0[0]), bw0.x);
    float o0y = fmaf(rstd, fmaf(-mean, gw0.y, acc0[1]), bw0.y);
    float o0z = fmaf(rstd, fmaf(-mean, gw0.z, acc0[2]), bw0.z);
    float o0w = fmaf(rstd, fmaf(-mean, gw0.w, acc0[3]), bw0.w);
    float o1x = fmaf(rstd, fmaf(-mean, gw1.x, acc1[0]), bw1.x);
    float o1y = fmaf(rstd, fmaf(-mean, gw1.y, acc1[1]), bw1.y);
    float o1z = fmaf(rstd, fmaf(-mean, gw1.z, acc1[2]), bw1.z);
    float o1w = fmaf(rstd, fmaf(-mean, gw1.w, acc1[3]), bw1.w);

    if (is_k) {
        // bf16 store: row of 32 bf16; lane writes j0=quad*4 (+16)
        unsigned short* orow = kwb + (((size_t)b * W_ + pos) * H_ + h) * MID_;
        uint2 u0, u1;
        u0.x = bfpair(o0x, o0y); u0.y = bfpair(o0z, o0w);
        u1.x = bfpair(o1x, o1y); u1.y = bfpair(o1z, o1w);
        *(uint2*)(orow + quad * 4)      = u0;
        *(uint2*)(orow + 16 + quad * 4) = u1;
    } else {
        float* orow = qv + ((size_t)b * M_ + pos) * MID_;
        *(float4*)(orow + quad * 4)      = make_float4(o0x, o0y, o0z, o0w);
        *(float4*)(orow + 16 + quad * 4) = make_float4(o1x, o1y, o1z, o1w);
        // ---- fused bucket scatter (one thread per m) ----
        if (quad == 0) {
            const int bm = b * M_ + pos;
            int w = u[bm];
            w = min(max(w, 0), W_ - 1);
            const int bw = b * W_ + w;
            const int p = atomicAdd(&counts[bw], 1);
            if (p < CAP_) bucket[bw * CAP_ + p] = bm;
            else          olist[atomicAdd(ocount, 1)] = bm;
        }
    }
}

// ---------------------------------------------------------------------------
// Bucketed attention: block per (b,w); each wave hoists its (bf16) k row and
// v values ONCE (unpack outside the m-loop), then loops over the bucket's
// m's. Tail blocks process overflow entries (dead in practice).
// ---------------------------------------------------------------------------
__global__ __launch_bounds__(256) void battn_kernel(
    const float* __restrict__ qv,      // [B, M, MID]
    const unsigned short* __restrict__ kwb, // [B, W, H, MID] bf16
    const float* __restrict__ gh,      // [B, 1, H, W]
    const int*   __restrict__ u,       // [B, M]
    const int*   __restrict__ counts,  // [B*W]
    const int*   __restrict__ bucket,  // [B*W][CAP_]
    const int*   __restrict__ ocount,  // [1]
    const int*   __restrict__ olist,   // [B*M]
    float* __restrict__ out)           // [B, M]
{
    const int blk  = blockIdx.x;
    const int tid  = threadIdx.x;
    const int lane = tid & 63;
    const int wv   = __builtin_amdgcn_readfirstlane(tid >> 6);
    const float sc = 0.17677669529663687f;           // 32^-0.5

    if (blk >= B_ * W_) {
        // ---- overflow tail (runs only if a bucket exceeded CAP_) ----
        const int nof = min(*ocount, B_ * M_);
        const int gwv = (blk - B_ * W_) * 4 + wv;
        for (int i = gwv; i < nof; i += OBLK * 4) {
            const int bm = olist[i];
            const int b  = bm >> 12;
            int w = u[bm];
            w = min(max(w, 0), W_ - 1);
            const unsigned short* kr = kwb + ((size_t)b * W_ + w) * H_ * MID_;
            const float* qr = qv + (size_t)bm * MID_;
            float sq[MID_];
#pragma unroll
            for (int j = 0; j < MID_; ++j) sq[j] = qr[j];
            float d0 = 0.f, d1 = 0.f;
#pragma unroll
            for (int j = 0; j < MID_; ++j) {
                d0 = fmaf(sq[j], __uint_as_float((unsigned)kr[lane * MID_ + j] << 16), d0);
                d1 = fmaf(sq[j], __uint_as_float((unsigned)kr[(lane + 64) * MID_ + j] << 16), d1);
            }
            d0 *= sc; d1 *= sc;
            float mx = fmaxf(d0, d1);
#pragma unroll
            for (int o = 32; o > 0; o >>= 1) mx = fmaxf(mx, __shfl_xor(mx, o, 64));
            const float v0 = gh[((size_t)b * H_ + lane) * W_ + w];
            const float v1 = gh[((size_t)b * H_ + lane + 64) * W_ + w];
            const float e0 = __expf(d0 - mx);
            const float e1 = __expf(d1 - mx);
            float s   = e0 + e1;
            float svv = fmaf(e0, v0, e1 * v1);
#pragma unroll
            for (int o = 32; o > 0; o >>= 1) {
                s   += __shfl_xor(s,   o, 64);
                svv += __shfl_xor(svv, o, 64);
            }
            if (lane == 0) out[bm] = svv / s;
        }
        return;
    }

    const int n = min(counts[blk], CAP_);
    if (wv >= n) return;                             // wave-uniform exit

    const int b = blk >> 9;
    const int w = blk & (W_ - 1);

    // hoist + unpack k rows for h=lane and h=lane+64 (bf16 -> f32, once)
    const uint4* k4 = (const uint4*)(kwb + (size_t)blk * H_ * MID_);
    float ka[32], kb[32];
#pragma unroll
    for (int t = 0; t < 4; ++t) {
        const uint4 ua = k4[lane * 4 + t];
        const uint4 ub = k4[(lane + 64) * 4 + t];
        ka[t*8+0] = __uint_as_float(ua.x << 16); ka[t*8+1] = __uint_as_float(ua.x & 0xFFFF0000u);
        ka[t*8+2] = __uint_as_float(ua.y << 16); ka[t*8+3] = __uint_as_float(ua.y & 0xFFFF0000u);
        ka[t*8+4] = __uint_as_float(ua.z << 16); ka[t*8+5] = __uint_as_float(ua.z & 0xFFFF0000u);
        ka[t*8+6] = __uint_as_float(ua.w << 16); ka[t*8+7] = __uint_as_float(ua.w & 0xFFFF0000u);
        kb[t*8+0] = __uint_as_float(ub.x << 16); kb[t*8+1] = __uint_as_float(ub.x & 0xFFFF0000u);
        kb[t*8+2] = __uint_as_float(ub.y << 16); kb[t*8+3] = __uint_as_float(ub.y & 0xFFFF0000u);
        kb[t*8+4] = __uint_as_float(ub.z << 16); kb[t*8+5] = __uint_as_float(ub.z & 0xFFFF0000u);
        kb[t*8+6] = __uint_as_float(ub.w << 16); kb[t*8+7] = __uint_as_float(ub.w & 0xFFFF0000u);
    }

    const float v0 = gh[((size_t)b * H_ + lane) * W_ + w];
    const float v1 = gh[((size_t)b * H_ + lane + 64) * W_ + w];

    const int* bkt = bucket + (size_t)blk * CAP_;

    for (int i = wv; i < n; i += 4) {
        const int bm = bkt[i];                       // wave-uniform
        const float* qr = qv + (size_t)bm * MID_;
        float sq[MID_];
#pragma unroll
        for (int j = 0; j < MID_; ++j) sq[j] = qr[j];

        float d0 = 0.f, d1 = 0.f;
#pragma unroll
        for (int j = 0; j < MID_; ++j) {
            d0 = fmaf(sq[j], ka[j], d0);
            d1 = fmaf(sq[j], kb[j], d1);
        }
        d0 *= sc; d1 *= sc;

        float mx = fmaxf(d0, d1);
#pragma unroll
        for (int o = 32; o > 0; o >>= 1) mx = fmaxf(mx, __shfl_xor(mx, o, 64));

        const float e0 = __expf(d0 - mx);
        const float e1 = __expf(d1 - mx);
        float s   = e0 + e1;
        float svv = fmaf(e0, v0, e1 * v1);
#pragma unroll
        for (int o = 32; o > 0; o >>= 1) {
            s   += __shfl_xor(s,   o, 64);
            svv += __shfl_xor(svv, o, 64);
        }

        if (lane == 0) out[bm] = svv / s;
    }
}

// ---------------------------------------------------------------------------
extern "C" void kernel_launch(void* const* d_in, const int* in_sizes, int n_in,
                              void* d_out, int out_size, void* d_ws, size_t ws_size,
                              hipStream_t stream) {
    const float* sat_x      = (const float*)d_in[0];
    const float* grd_x      = (const float*)d_in[1];
    const float* grd_height = (const float*)d_in[2];
    const int*   u          = (const int*)d_in[3];
    const float* ln_q_g     = (const float*)d_in[4];
    const float* ln_q_b     = (const float*)d_in[5];
    const float* wq         = (const float*)d_in[6];
    const float* bq         = (const float*)d_in[7];
    const float* ln_k_g     = (const float*)d_in[8];
    const float* ln_k_b     = (const float*)d_in[9];
    const float* wk         = (const float*)d_in[10];
    const float* bk         = (const float*)d_in[11];

    float* out = (float*)d_out;

    // workspace layout
    char* ws = (char*)d_ws;
    unsigned short* kwb = (unsigned short*)ws;                        // 8 MB (bf16)
    float* q       = (float*)(ws + (size_t)8  * 1024 * 1024);         // 1 MB
    int*   counts  = (int*)  (ws + (size_t)9  * 1024 * 1024);         // 4 KB
    int*   ocount  = (int*)  (ws + (size_t)9  * 1024 * 1024 + 4096);  // 4 KB pad
    int*   bucket  = (int*)  (ws + (size_t)9  * 1024 * 1024 + 8192);  // 768 KB
    int*   olist   = bucket + B_ * W_ * CAP_;                          // 32 KB
    float* prepbuf = (float*)(ws + (size_t)10 * 1024 * 1024);         // 512 B
    short* wfrag   = (short*)(ws + (size_t)10 * 1024 * 1024 + 4096);  // 32 KB

    prep_kernel<<<2, 256, 0, stream>>>(
        ln_k_g, ln_k_b, wk, bk, ln_q_g, ln_q_b, wq, bq,
        prepbuf, wfrag, counts, ocount);
    proj_kernel<<<KBLK + QBLK, 256, 0, stream>>>(
        grd_x, sat_x, prepbuf, wfrag, u, kwb, q, counts, bucket, ocount, olist);
    battn_kernel<<<B_ * W_ + OBLK, 256, 0, stream>>>(
        q, kwb, grd_height, u, counts, bucket, ocount, olist, out);
}